// Round 8
// baseline (198.106 us; speedup 1.0000x reference)
//
#include <hip/hip_runtime.h>

typedef unsigned short u16;
typedef __attribute__((ext_vector_type(8))) short short8;
typedef __attribute__((ext_vector_type(4))) short short4v;
typedef __attribute__((ext_vector_type(4))) float f32x4;
typedef __attribute__((ext_vector_type(16))) float f32x16;

#define MFMA16(a, b, c) __builtin_amdgcn_mfma_f32_16x16x32_bf16(a, b, c, 0, 0, 0)
#define MFMA32(a, b, c) __builtin_amdgcn_mfma_f32_32x32x16_bf16(a, b, c, 0, 0, 0)

#define BB 8
#define NN 1024
#define DD 1024
#define HH 16
#define HD 64
#define MM (BB * NN)
// 0.125 (hd^-0.5) * log2(e): softmax computed in exp2 domain
#define SCLOG2 0.18033688011112042f

#define WAIT_VM(N) asm volatile("s_waitcnt vmcnt(" #N ")" ::: "memory")
#define WAIT_LGKM0() asm volatile("s_waitcnt lgkmcnt(0)" ::: "memory")

static __device__ __forceinline__ u16 f2bf(float f) {
  unsigned u = __float_as_uint(f);
  u += 0x7fffu + ((u >> 16) & 1u);  // RNE
  return (u16)(u >> 16);
}

static __device__ __forceinline__ void gld16(const void* g, void* l) {
  __builtin_amdgcn_global_load_lds((const __attribute__((address_space(1))) void*)g,
                                   (__attribute__((address_space(3))) void*)l, 16, 0, 0);
}

static __device__ __forceinline__ unsigned cvtpk(float lo, float hi) {
  unsigned r;
  asm("v_cvt_pk_bf16_f32 %0, %1, %2" : "=v"(r) : "v"(lo), "v"(hi));
  return r;
}

static __device__ __forceinline__ f32x16 zero16() {
  f32x16 v;
#pragma unroll
  for (int i = 0; i < 16; ++i) v[i] = 0.f;
  return v;
}

// ---------------- lengths from mask (auto-detect bool-byte vs int32) --------
__global__ void lens_kernel(const unsigned char* __restrict__ mask, int* __restrict__ lens) {
  __shared__ int acc[BB];
  const int t = threadIdx.x;
  if (t < BB) acc[t] = 0;
  __syncthreads();
  const bool isbyte = (mask[1] != 0);  // lengths >= 512 so element 1 is true
  for (int b = 0; b < BB; ++b) {
    int s = 0;
    if (isbyte) {
      for (int i = t; i < NN; i += 256) s += mask[(size_t)b * NN + i] ? 1 : 0;
    } else {
      const int* mi = (const int*)mask;
      for (int i = t; i < NN; i += 256) s += mi[(size_t)b * NN + i] != 0 ? 1 : 0;
    }
    if (s) atomicAdd(&acc[b], s);
  }
  __syncthreads();
  if (t < BB) lens[t] = acc[t];
}

// ---------------- f32 -> bf16 cast (8 elems/thread) -------------------------
__global__ __launch_bounds__(256) void cast_bf16_kernel(const float* __restrict__ in,
                                                        u16* __restrict__ out, int n8) {
  const int i = blockIdx.x * 256 + threadIdx.x;
  if (i >= n8) return;
  const f32x4* p = (const f32x4*)in + (size_t)i * 2;
  const f32x4 a = p[0], b = p[1];
  short8 o;
  o[0] = (short)f2bf(a[0]); o[1] = (short)f2bf(a[1]);
  o[2] = (short)f2bf(a[2]); o[3] = (short)f2bf(a[3]);
  o[4] = (short)f2bf(b[0]); o[5] = (short)f2bf(b[1]);
  o[6] = (short)f2bf(b[2]); o[7] = (short)f2bf(b[3]);
  *(short8*)(out + (size_t)i * 8) = o;
}

// ---------------- fused cast of the 4 weight matrices -----------------------
__global__ __launch_bounds__(256) void cast4_bf16_kernel(const float* __restrict__ a, const float* __restrict__ b,
                                                         const float* __restrict__ c, const float* __restrict__ d,
                                                         u16* __restrict__ oa, u16* __restrict__ ob,
                                                         u16* __restrict__ oc, u16* __restrict__ od) {
  const int i = blockIdx.x * 256 + threadIdx.x;
  const float* in;
  u16* out;
  switch (blockIdx.y) {
    case 0: in = a; out = oa; break;
    case 1: in = b; out = ob; break;
    case 2: in = c; out = oc; break;
    default: in = d; out = od; break;
  }
  const f32x4* p = (const f32x4*)in + (size_t)i * 2;
  const f32x4 va = p[0], vb = p[1];
  short8 o;
  o[0] = (short)f2bf(va[0]); o[1] = (short)f2bf(va[1]);
  o[2] = (short)f2bf(va[2]); o[3] = (short)f2bf(va[3]);
  o[4] = (short)f2bf(vb[0]); o[5] = (short)f2bf(vb[1]);
  o[6] = (short)f2bf(vb[2]); o[7] = (short)f2bf(vb[3]);
  *(short8*)(out + (size_t)i * 8) = o;
}

// ====== GEMM core v3: 128x128, BK=32, dbuf + T4 counted vmcnt ==============
// Swizzle (fixed from R7): byte ^= ((row>>1)&3)<<4 on BOTH gld16 source col
// and ds_read addr. A b128 quarter-wave reads 16 rows at 64B stride; XOR with
// row bits 2:1 puts exactly 2 lanes/bank (free). (row&3 paired same-XOR rows
// 2 apart -> 4-way, the R7 bug.)
// Pipeline: STAGE(next) -> vmcnt(4) [current tile's loads, issued LAST iter;
// next tile's 4 stay in flight across the barrier] -> B1 -> ds_read+MFMA ->
// lgkm0 -> B2 (reads done before next overwrite). NO vmcnt(0) drain in loop.
#define STAGE_G(d, k0_)                                                            \
  _Pragma("unroll") for (int p = 0; p < 2; ++p) {                                  \
    const int off = (p * 256 + t) * 16;                                            \
    const int row = off >> 6;                                                      \
    const int colb = (off & 63) ^ (((row >> 1) & 3) << 4);                         \
    gld16(Ag + (size_t)(m0 + row) * 1024 + (k0_) + (colb >> 1), &As[d][off >> 1]); \
    gld16(Bg + (size_t)(n0 + row) * 1024 + (k0_) + (colb >> 1), &Bs[d][off >> 1]); \
  }

#define GEMM_CORE3()                                                            \
  STAGE_G(0, 0)                                                                 \
  for (int k0 = 0; k0 < 1024; k0 += 32) {                                       \
    const int cur = (k0 >> 5) & 1;                                              \
    if (k0 + 32 < 1024) {                                                       \
      STAGE_G(cur ^ 1, k0 + 32)                                                 \
      WAIT_VM(4);                                                               \
    } else {                                                                    \
      WAIT_VM(0);                                                               \
    }                                                                           \
    __builtin_amdgcn_s_barrier(); /* B1: current tile visible to all waves */   \
    __builtin_amdgcn_sched_barrier(0);                                          \
    short8 af[4], bf[4];                                                        \
    _Pragma("unroll") for (int mi = 0; mi < 4; ++mi) {                          \
      const int row = wr * 64 + mi * 16 + li;                                   \
      const int byo = row * 64 + ((lg * 16) ^ (((row >> 1) & 3) << 4));         \
      af[mi] = *(const short8*)((const char*)&As[cur][0] + byo);                \
    }                                                                           \
    _Pragma("unroll") for (int ni = 0; ni < 4; ++ni) {                          \
      const int row = wc * 64 + ni * 16 + li;                                   \
      const int byo = row * 64 + ((lg * 16) ^ (((row >> 1) & 3) << 4));         \
      bf[ni] = *(const short8*)((const char*)&Bs[cur][0] + byo);                \
    }                                                                           \
    WAIT_LGKM0();                                                               \
    __builtin_amdgcn_sched_barrier(0);                                          \
    __builtin_amdgcn_s_setprio(1);                                              \
    _Pragma("unroll") for (int mi = 0; mi < 4; ++mi)                            \
      _Pragma("unroll") for (int ni = 0; ni < 4; ++ni)                          \
          acc[mi][ni] = MFMA16(af[mi], bf[ni], acc[mi][ni]);                    \
    __builtin_amdgcn_s_setprio(0);                                              \
    __builtin_amdgcn_sched_barrier(0);                                          \
    __builtin_amdgcn_s_barrier(); /* B2: all reads of cur done */               \
  }

// ---------------- fused QKV projection: C_m = xb @ W_m^T, m in {k,q,v} ------
__global__ __launch_bounds__(256) void gemm_qkv(const u16* __restrict__ A,
                                                const u16* __restrict__ Wk3, const u16* __restrict__ Wq3,
                                                const u16* __restrict__ Wv3,
                                                u16* __restrict__ kb, u16* __restrict__ qb,
                                                u16* __restrict__ vtb, const int* __restrict__ lens) {
  const int m0 = blockIdx.x * 128;
  if ((m0 & 1023) >= lens[m0 >> 10]) return;  // dead rows
  __shared__ u16 As[2][4096];
  __shared__ u16 Bs[2][4096];
  const int mat = blockIdx.y >> 3;
  const int n0 = (blockIdx.y & 7) * 128;
  const u16* Ag = A;
  const u16* Bg = (mat == 0) ? Wk3 : (mat == 1) ? Wq3 : Wv3;
  const int t = threadIdx.x;
  const int lane = t & 63;
  const int w = t >> 6;
  const int wr = w >> 1, wc = w & 1;
  const int li = lane & 15, lg = lane >> 4;
  f32x4 acc[4][4] = {};

  GEMM_CORE3()

  if (mat == 2) {  // V: transposed per-head store
#pragma unroll
    for (int mi = 0; mi < 4; ++mi) {
      const int row = m0 + wr * 64 + mi * 16 + lg * 4;  // (b, j)
      const int bb = row >> 10, jj = row & 1023;
#pragma unroll
      for (int ni = 0; ni < 4; ++ni) {
        const int col = n0 + wc * 64 + ni * 16 + li;  // (h, x)
        const int h = col >> 6, x = col & 63;
        short4v st;
#pragma unroll
        for (int r = 0; r < 4; ++r) st[r] = (short)f2bf(acc[mi][ni][r]);
        *(short4v*)(vtb + ((size_t)((bb * HH + h) * HD + x)) * NN + jj) = st;
      }
    }
  } else {
    u16* C = (mat == 0) ? kb : qb;
    const float scale = (mat == 0) ? SCLOG2 : 1.0f;
#pragma unroll
    for (int mi = 0; mi < 4; ++mi)
#pragma unroll
      for (int ni = 0; ni < 4; ++ni) {
        const int col = n0 + wc * 64 + ni * 16 + li;
        const int rowb = m0 + wr * 64 + mi * 16 + lg * 4;
#pragma unroll
        for (int r = 0; r < 4; ++r)
          C[(size_t)(rowb + r) * 1024 + col] = f2bf(acc[mi][ni][r] * scale);
      }
  }
}

// ---------------- output GEMM: out = attb @ Wo^T + bo, mask-zeroed ----------
__global__ __launch_bounds__(256) void gemm_out(const u16* __restrict__ A, const u16* __restrict__ Bw,
                                                float* __restrict__ C, const float* __restrict__ bias,
                                                const int* __restrict__ lens) {
  const int m0 = blockIdx.x * 128;
  const int n0 = blockIdx.y * 128;
  const int t = threadIdx.x;
  if ((m0 & 1023) >= lens[m0 >> 10]) {  // fully-masked tile: store zeros only
    const int r = t >> 1, ch = (t & 1) * 64;
    float* Crow = C + (size_t)(m0 + r) * 1024 + n0 + ch;
    const f32x4 z = {0.f, 0.f, 0.f, 0.f};
#pragma unroll
    for (int c = 0; c < 16; ++c) *(f32x4*)(Crow + c * 4) = z;
    return;
  }
  __shared__ u16 As[2][4096];
  __shared__ u16 Bs[2][4096];
  const u16* Ag = A;
  const u16* Bg = Bw;
  const int lane = t & 63;
  const int w = t >> 6;
  const int wr = w >> 1, wc = w & 1;
  const int li = lane & 15, lg = lane >> 4;
  f32x4 acc[4][4] = {};

  GEMM_CORE3()

#pragma unroll
  for (int ni = 0; ni < 4; ++ni) {
    const int col = n0 + wc * 64 + ni * 16 + li;
    const float bv = bias[col];
#pragma unroll
    for (int mi = 0; mi < 4; ++mi) {
      const int rowb = m0 + wr * 64 + mi * 16 + lg * 4;
#pragma unroll
      for (int r = 0; r < 4; ++r) {
        const int row = rowb + r;
        const int bb = row >> 10, ii = row & 1023;
        const float v = (ii < lens[bb]) ? (acc[mi][ni][r] + bv) : 0.f;
        C[(size_t)row * 1024 + col] = v;
      }
    }
  }
}

// ---------------- flash attention, 4 waves/block, 32 i-rows/wave ------------
// LDS double-buffered Q/V staging + T4 counted vmcnt (the __syncthreads in
// R3-R7 drained the same-iteration prefetch; now only the CURRENT tile's 4
// loads are waited, prefetch stays in flight across the barrier).
// Load-balanced XCD swizzle: bid = [b(3)|hbit(1)|ic(3)|xcd(3)].
// S^T = mfma32(A=Q-frag, B=K-frag): lane l holds col i = l&31,
// row j = (reg&3) + 8*(reg>>2) + 4*(l>>5). Scores in exp2 domain.
__global__ __launch_bounds__(256) void attn_kernel(const u16* __restrict__ Kb, const u16* __restrict__ Qb,
                                                   const u16* __restrict__ Vtb, u16* __restrict__ attb,
                                                   const int* __restrict__ lens) {
  const int bid = blockIdx.x;
  const int b = bid >> 7;
  const int ic = (bid >> 3) & 7;
  const int h = ((bid & 7) << 1) | ((bid >> 6) & 1);
  const int len = lens[b];
  const int i0 = ic * 128;
  if (i0 >= len) return;  // fully-masked rows zeroed by final GEMM
  const int t = threadIdx.x;
  const int w = t >> 6, l = t & 63;
  const int l31 = l & 31, hi = l >> 5;
  const int i0w = i0 + w * 32;

  __shared__ u16 Qs[2][4096];  // 8KB per buffer
  __shared__ u16 Vs[2][4096];

  // K fragments (B operand): col i = l31, k(hd) = ks*16 + hi*8 + e
  short8 kf[4];
  {
    const u16* kp = Kb + ((size_t)(b * NN + i0w + l31)) * DD + h * HD + hi * 8;
#pragma unroll
    for (int ks = 0; ks < 4; ++ks) kf[ks] = *(const short8*)(kp + ks * 16);
  }

  const size_t qsrc = ((size_t)(b * NN) + l31) * DD + h * HD + w * 16 + hi * 8;
  const size_t vsrc = ((size_t)((b * HH + h) * HD + l31)) * NN + w * 16 + hi * 8;

  auto STAGE = [&](int buf, int j0) {
    u16* qd = &Qs[buf][0] + t * 8;
    u16* vd = &Vs[buf][0] + t * 8;
    gld16(Qb + qsrc + (size_t)j0 * DD, qd);
    gld16(Qb + qsrc + (size_t)(j0 + 32) * DD, qd + 2048);
    gld16(Vtb + vsrc + j0, vd);
    gld16(Vtb + vsrc + 32 * NN + j0, vd + 2048);
  };

  f32x16 o0 = zero16(), o1 = zero16();
  float m_run = -3.0e38f, l_run = 0.f;
  const int nt = (len + 63) >> 6;

  STAGE(0, 0);
  for (int jt = 0; jt < nt; ++jt) {
    const int cur = jt & 1;
    const int j0 = jt * 64;
    if (jt + 1 < nt) {
      STAGE(cur ^ 1, j0 + 64);  // prefetch: stays in flight across B1
      WAIT_VM(4);               // current tile's 4 loads (issued last iter)
    } else {
      WAIT_VM(0);
    }
    __builtin_amdgcn_s_barrier();  // B1: current Q/V tile visible
    __builtin_amdgcn_sched_barrier(0);

    const u16* Qc = &Qs[cur][0];
    const u16* Vc = &Vs[cur][0];
    f32x16 s0 = zero16(), s1 = zero16();
    __builtin_amdgcn_s_setprio(1);
#pragma unroll
    for (int ks = 0; ks < 4; ++ks) {
      const short8 qf = *(const short8*)(Qc + (ks * 64 + l) * 8);
      s0 = MFMA32(qf, kf[ks], s0);
    }
#pragma unroll
    for (int ks = 0; ks < 4; ++ks) {
      const short8 qf = *(const short8*)(Qc + ((4 + ks) * 64 + l) * 8);
      s1 = MFMA32(qf, kf[ks], s1);
    }
    __builtin_amdgcn_s_setprio(0);

    if (j0 + 64 > len) {  // uniform; only possible on last tile
#pragma unroll
      for (int r = 0; r < 16; ++r) {
        const int jl = (r & 3) + 8 * (r >> 2) + 4 * hi;
        if (j0 + jl >= len) s0[r] = -3.0e38f;
        if (j0 + 32 + jl >= len) s1[r] = -3.0e38f;
      }
    }

    float pmax = s0[0];
#pragma unroll
    for (int r = 1; r < 16; ++r) pmax = fmaxf(pmax, s0[r]);
#pragma unroll
    for (int r = 0; r < 16; ++r) pmax = fmaxf(pmax, s1[r]);
    pmax = fmaxf(pmax, __shfl_xor(pmax, 32));

    // defer-max (T13): skip O-rescale while tile max within 11.5 (log2) of m_run
    if (!__all(pmax <= m_run + 11.5f)) {
      const float mnew = fmaxf(m_run, pmax);
      const float al = __builtin_amdgcn_exp2f(m_run - mnew);
      l_run *= al;
#pragma unroll
      for (int r = 0; r < 16; ++r) { o0[r] *= al; o1[r] *= al; }
      m_run = mnew;
    }

    float rs = 0.f;
#pragma unroll
    for (int r = 0; r < 16; ++r) { const float p = __builtin_amdgcn_exp2f(s0[r] - m_run); s0[r] = p; rs += p; }
#pragma unroll
    for (int r = 0; r < 16; ++r) { const float p = __builtin_amdgcn_exp2f(s1[r] - m_run); s1[r] = p; rs += p; }
    rs += __shfl_xor(rs, 32);
    l_run += rs;

    // P -> PV B-fragments: per 16-j chunk, 4 cvt_pk + 2 permlane32_swap (T12).
    short8 pf[4];
#pragma unroll
    for (int jk = 0; jk < 4; ++jk) {
      const f32x16& ss = (jk < 2) ? s0 : s1;
      const int kk = jk & 1;
      unsigned W0 = cvtpk(ss[8 * kk + 0], ss[8 * kk + 1]);
      unsigned W1 = cvtpk(ss[8 * kk + 2], ss[8 * kk + 3]);
      unsigned W2 = cvtpk(ss[8 * kk + 4], ss[8 * kk + 5]);
      unsigned W3 = cvtpk(ss[8 * kk + 6], ss[8 * kk + 7]);
      asm("v_permlane32_swap_b32 %0, %1" : "+v"(W0), "+v"(W2));
      asm("v_permlane32_swap_b32 %0, %1" : "+v"(W1), "+v"(W3));
      union { unsigned u[4]; short8 s; } pu;
      pu.u[0] = W0; pu.u[1] = W1; pu.u[2] = W2; pu.u[3] = W3;
      pf[jk] = pu.s;
    }

    __builtin_amdgcn_s_setprio(1);
#pragma unroll
    for (int kkg = 0; kkg < 4; ++kkg) {
      const short8 vf = *(const short8*)(Vc + (kkg * 64 + l) * 8);
      o0 = MFMA32(vf, pf[kkg], o0);
    }
#pragma unroll
    for (int kkg = 0; kkg < 4; ++kkg) {
      const short8 vf = *(const short8*)(Vc + ((4 + kkg) * 64 + l) * 8);
      o1 = MFMA32(vf, pf[kkg], o1);
    }
    __builtin_amdgcn_s_setprio(0);

    WAIT_LGKM0();  // this wave's ds_reads of cur complete
    __builtin_amdgcn_sched_barrier(0);
    __builtin_amdgcn_s_barrier();  // B2: safe to overwrite cur next iter
  }

  const float inv = 1.f / l_run;
  u16* op = attb + (size_t)(b * NN + i0w + l31) * DD + h * HD + hi * 4;
#pragma unroll
  for (int xs = 0; xs < 2; ++xs) {
    const f32x16& oo = xs ? o1 : o0;
#pragma unroll
    for (int q = 0; q < 4; ++q) {
      short4v st;
#pragma unroll
      for (int e = 0; e < 4; ++e) st[e] = (short)f2bf(oo[q * 4 + e] * inv);
      *(short4v*)(op + xs * 32 + q * 8) = st;
    }
  }
}

// ---------------------------------------------------------------------------
extern "C" void kernel_launch(void* const* d_in, const int* in_sizes, int n_in,
                              void* d_out, int out_size, void* d_ws, size_t ws_size,
                              hipStream_t stream) {
  const float* x = (const float*)d_in[0];
  const unsigned char* mask = (const unsigned char*)d_in[1];
  const float* Wk = (const float*)d_in[2];
  const float* Wq = (const float*)d_in[3];
  const float* Wv = (const float*)d_in[4];
  const float* Wo = (const float*)d_in[5];
  const float* bo = (const float*)d_in[6];
  float* out = (float*)d_out;

  char* ws = (char*)d_ws;
  size_t o = 0;
  int* lens = (int*)(ws + o); o += 256;
  u16* xb  = (u16*)(ws + o); o += (size_t)MM * DD * 2;
  u16* wkb = (u16*)(ws + o); o += (size_t)DD * DD * 2;
  u16* wqb = (u16*)(ws + o); o += (size_t)DD * DD * 2;
  u16* wvb = (u16*)(ws + o); o += (size_t)DD * DD * 2;
  u16* wob = (u16*)(ws + o); o += (size_t)DD * DD * 2;
  u16* kb  = (u16*)(ws + o); o += (size_t)MM * DD * 2;
  u16* qb  = (u16*)(ws + o); o += (size_t)MM * DD * 2;
  u16* vtb = (u16*)(ws + o); o += (size_t)MM * DD * 2;
  u16* attb = xb;  // alias: x only needed until projections finish

  lens_kernel<<<dim3(1), dim3(256), 0, stream>>>(mask, lens);

  const int xn8 = MM * DD / 8;
  cast_bf16_kernel<<<dim3(xn8 / 256), dim3(256), 0, stream>>>(x, xb, xn8);
  cast4_bf16_kernel<<<dim3(DD * DD / 8 / 256, 4), dim3(256), 0, stream>>>(
      Wk, Wq, Wv, Wo, wkb, wqb, wvb, wob);

  gemm_qkv<<<dim3(MM / 128, 24), dim3(256), 0, stream>>>(xb, wkb, wqb, wvb, kb, qb, vtb, lens);

  attn_kernel<<<dim3(1024), dim3(256), 0, stream>>>(kb, qb, vtb, attb, lens);

  gemm_out<<<dim3(MM / 128, DD / 128), dim3(256), 0, stream>>>(attb, wob, out, bo, lens);
}

// Round 9
// 184.028 us; speedup vs baseline: 1.0765x; 1.0765x over previous
//
#include <hip/hip_runtime.h>

typedef unsigned short u16;
typedef __attribute__((ext_vector_type(8))) short short8;
typedef __attribute__((ext_vector_type(4))) short short4v;
typedef __attribute__((ext_vector_type(4))) float f32x4;
typedef __attribute__((ext_vector_type(16))) float f32x16;

#define MFMA16(a, b, c) __builtin_amdgcn_mfma_f32_16x16x32_bf16(a, b, c, 0, 0, 0)
#define MFMA32(a, b, c) __builtin_amdgcn_mfma_f32_32x32x16_bf16(a, b, c, 0, 0, 0)

#define BB 8
#define NN 1024
#define DD 1024
#define HH 16
#define HD 64
#define MM (BB * NN)
// 0.125 (hd^-0.5) * log2(e): softmax computed in exp2 domain
#define SCLOG2 0.18033688011112042f

static __device__ __forceinline__ u16 f2bf(float f) {
  unsigned u = __float_as_uint(f);
  u += 0x7fffu + ((u >> 16) & 1u);  // RNE
  return (u16)(u >> 16);
}

static __device__ __forceinline__ void gld16(const void* g, void* l) {
  __builtin_amdgcn_global_load_lds((const __attribute__((address_space(1))) void*)g,
                                   (__attribute__((address_space(3))) void*)l, 16, 0, 0);
}

static __device__ __forceinline__ unsigned cvtpk(float lo, float hi) {
  unsigned r;
  asm("v_cvt_pk_bf16_f32 %0, %1, %2" : "=v"(r) : "v"(lo), "v"(hi));
  return r;
}

static __device__ __forceinline__ f32x16 zero16() {
  f32x16 v;
#pragma unroll
  for (int i = 0; i < 16; ++i) v[i] = 0.f;
  return v;
}

// ---------------- f32 -> bf16 cast (8 elems/thread) -------------------------
__global__ __launch_bounds__(256) void cast_bf16_kernel(const float* __restrict__ in,
                                                        u16* __restrict__ out, int n8) {
  const int i = blockIdx.x * 256 + threadIdx.x;
  if (i >= n8) return;
  const f32x4* p = (const f32x4*)in + (size_t)i * 2;
  const f32x4 a = p[0], b = p[1];
  short8 o;
  o[0] = (short)f2bf(a[0]); o[1] = (short)f2bf(a[1]);
  o[2] = (short)f2bf(a[2]); o[3] = (short)f2bf(a[3]);
  o[4] = (short)f2bf(b[0]); o[5] = (short)f2bf(b[1]);
  o[6] = (short)f2bf(b[2]); o[7] = (short)f2bf(b[3]);
  *(short8*)(out + (size_t)i * 8) = o;
}

// ------- fused cast of the 4 weight matrices + lens (y==4 plane) ------------
__global__ __launch_bounds__(256) void cast4_lens_kernel(const float* __restrict__ a, const float* __restrict__ b,
                                                         const float* __restrict__ c, const float* __restrict__ d,
                                                         u16* __restrict__ oa, u16* __restrict__ ob,
                                                         u16* __restrict__ oc, u16* __restrict__ od,
                                                         const unsigned char* __restrict__ mask,
                                                         int* __restrict__ lens) {
  if (blockIdx.y == 4) {  // lens plane: only block x==0 works
    if (blockIdx.x != 0) return;
    __shared__ int acc[BB];
    const int t = threadIdx.x;
    if (t < BB) acc[t] = 0;
    __syncthreads();
    const bool isbyte = (mask[1] != 0);  // lengths >= 512 so element 1 is true
    for (int bb = 0; bb < BB; ++bb) {
      int s = 0;
      if (isbyte) {
        for (int i = t; i < NN; i += 256) s += mask[(size_t)bb * NN + i] ? 1 : 0;
      } else {
        const int* mi = (const int*)mask;
        for (int i = t; i < NN; i += 256) s += mi[(size_t)bb * NN + i] != 0 ? 1 : 0;
      }
      if (s) atomicAdd(&acc[bb], s);
    }
    __syncthreads();
    if (t < BB) lens[t] = acc[t];
    return;
  }
  const int i = blockIdx.x * 256 + threadIdx.x;
  const float* in;
  u16* out;
  switch (blockIdx.y) {
    case 0: in = a; out = oa; break;
    case 1: in = b; out = ob; break;
    case 2: in = c; out = oc; break;
    default: in = d; out = od; break;
  }
  const f32x4* p = (const f32x4*)in + (size_t)i * 2;
  const f32x4 va = p[0], vb = p[1];
  short8 o;
  o[0] = (short)f2bf(va[0]); o[1] = (short)f2bf(va[1]);
  o[2] = (short)f2bf(va[2]); o[3] = (short)f2bf(va[3]);
  o[4] = (short)f2bf(vb[0]); o[5] = (short)f2bf(vb[1]);
  o[6] = (short)f2bf(vb[2]); o[7] = (short)f2bf(vb[3]);
  *(short8*)(out + (size_t)i * 8) = o;
}

// ====== GEMM core: 128x128, BK=32, cross-tile dbuf, fixed T2 swizzle =======
// R7 pipeline (best measured): STAGE(buf^1, k+1) issued BEFORE compute(buf),
// ONE __syncthreads per K-step (drains vmcnt+lgkm and barriers in one).
// Swizzle (R8-verified conflict-free): byte ^= ((row>>1)&3)<<4 on BOTH the
// gld16 global source column and the ds_read addr (involution; LDS dest
// linear per rule 21). A b128 quarter-wave spans 16 rows x 64B: row bits 2:1
// in the XOR give exactly 2 lanes/bank (free per m136). (R7's (row&3)<<4
// left a 4-way conflict: rows 2 apart shared the same XOR.)
#define STAGE_G(d, k0_)                                                            \
  _Pragma("unroll") for (int p = 0; p < 2; ++p) {                                  \
    const int off = (p * 256 + t) * 16;                                            \
    const int row = off >> 6;                                                      \
    const int colb = (off & 63) ^ (((row >> 1) & 3) << 4);                         \
    gld16(Ag + (size_t)(m0 + row) * 1024 + (k0_) + (colb >> 1), &As[d][off >> 1]); \
    gld16(Bg + (size_t)(n0 + row) * 1024 + (k0_) + (colb >> 1), &Bs[d][off >> 1]); \
  }

#define GEMM_CORE2()                                                            \
  STAGE_G(0, 0)                                                                 \
  __syncthreads();                                                              \
  for (int k0 = 0; k0 < 1024; k0 += 32) {                                       \
    const int cur = (k0 >> 5) & 1;                                              \
    if (k0 + 32 < 1024) { STAGE_G(cur ^ 1, k0 + 32) }                           \
    short8 af[4], bf[4];                                                        \
    _Pragma("unroll") for (int mi = 0; mi < 4; ++mi) {                          \
      const int row = wr * 64 + mi * 16 + li;                                   \
      const int byo = row * 64 + ((lg * 16) ^ (((row >> 1) & 3) << 4));         \
      af[mi] = *(const short8*)((const char*)&As[cur][0] + byo);                \
    }                                                                           \
    _Pragma("unroll") for (int ni = 0; ni < 4; ++ni) {                          \
      const int row = wc * 64 + ni * 16 + li;                                   \
      const int byo = row * 64 + ((lg * 16) ^ (((row >> 1) & 3) << 4));         \
      bf[ni] = *(const short8*)((const char*)&Bs[cur][0] + byo);                \
    }                                                                           \
    __builtin_amdgcn_s_setprio(1);                                              \
    _Pragma("unroll") for (int mi = 0; mi < 4; ++mi)                            \
      _Pragma("unroll") for (int ni = 0; ni < 4; ++ni)                          \
          acc[mi][ni] = MFMA16(af[mi], bf[ni], acc[mi][ni]);                    \
    __builtin_amdgcn_s_setprio(0);                                              \
    __syncthreads();                                                            \
  }

// ---------------- fused QKV projection: C_m = xb @ W_m^T, m in {k,q,v} ------
__global__ __launch_bounds__(256) void gemm_qkv(const u16* __restrict__ A,
                                                const u16* __restrict__ Wk3, const u16* __restrict__ Wq3,
                                                const u16* __restrict__ Wv3,
                                                u16* __restrict__ kb, u16* __restrict__ qb,
                                                u16* __restrict__ vtb, const int* __restrict__ lens) {
  const int m0 = blockIdx.x * 128;
  if ((m0 & 1023) >= lens[m0 >> 10]) return;  // dead rows
  __shared__ u16 As[2][4096];
  __shared__ u16 Bs[2][4096];
  const int mat = blockIdx.y >> 3;
  const int n0 = (blockIdx.y & 7) * 128;
  const u16* Ag = A;
  const u16* Bg = (mat == 0) ? Wk3 : (mat == 1) ? Wq3 : Wv3;
  const int t = threadIdx.x;
  const int lane = t & 63;
  const int w = t >> 6;
  const int wr = w >> 1, wc = w & 1;
  const int li = lane & 15, lg = lane >> 4;
  f32x4 acc[4][4] = {};

  GEMM_CORE2()

  if (mat == 2) {  // V: transposed per-head store
#pragma unroll
    for (int mi = 0; mi < 4; ++mi) {
      const int row = m0 + wr * 64 + mi * 16 + lg * 4;  // (b, j)
      const int bb = row >> 10, jj = row & 1023;
#pragma unroll
      for (int ni = 0; ni < 4; ++ni) {
        const int col = n0 + wc * 64 + ni * 16 + li;  // (h, x)
        const int h = col >> 6, x = col & 63;
        short4v st;
#pragma unroll
        for (int r = 0; r < 4; ++r) st[r] = (short)f2bf(acc[mi][ni][r]);
        *(short4v*)(vtb + ((size_t)((bb * HH + h) * HD + x)) * NN + jj) = st;
      }
    }
  } else {
    u16* C = (mat == 0) ? kb : qb;
    const float scale = (mat == 0) ? SCLOG2 : 1.0f;
#pragma unroll
    for (int mi = 0; mi < 4; ++mi)
#pragma unroll
      for (int ni = 0; ni < 4; ++ni) {
        const int col = n0 + wc * 64 + ni * 16 + li;
        const int rowb = m0 + wr * 64 + mi * 16 + lg * 4;
#pragma unroll
        for (int r = 0; r < 4; ++r)
          C[(size_t)(rowb + r) * 1024 + col] = f2bf(acc[mi][ni][r] * scale);
      }
  }
}

// ---------------- output GEMM: out = attb @ Wo^T + bo, mask-zeroed ----------
__global__ __launch_bounds__(256) void gemm_out(const u16* __restrict__ A, const u16* __restrict__ Bw,
                                                float* __restrict__ C, const float* __restrict__ bias,
                                                const int* __restrict__ lens) {
  const int m0 = blockIdx.x * 128;
  const int n0 = blockIdx.y * 128;
  const int t = threadIdx.x;
  if ((m0 & 1023) >= lens[m0 >> 10]) {  // fully-masked tile: store zeros only
    const int r = t >> 1, ch = (t & 1) * 64;
    float* Crow = C + (size_t)(m0 + r) * 1024 + n0 + ch;
    const f32x4 z = {0.f, 0.f, 0.f, 0.f};
#pragma unroll
    for (int c = 0; c < 16; ++c) *(f32x4*)(Crow + c * 4) = z;
    return;
  }
  __shared__ u16 As[2][4096];
  __shared__ u16 Bs[2][4096];
  const u16* Ag = A;
  const u16* Bg = Bw;
  const int lane = t & 63;
  const int w = t >> 6;
  const int wr = w >> 1, wc = w & 1;
  const int li = lane & 15, lg = lane >> 4;
  f32x4 acc[4][4] = {};

  GEMM_CORE2()

#pragma unroll
  for (int ni = 0; ni < 4; ++ni) {
    const int col = n0 + wc * 64 + ni * 16 + li;
    const float bv = bias[col];
#pragma unroll
    for (int mi = 0; mi < 4; ++mi) {
      const int rowb = m0 + wr * 64 + mi * 16 + lg * 4;
#pragma unroll
      for (int r = 0; r < 4; ++r) {
        const int row = rowb + r;
        const int bb = row >> 10, ii = row & 1023;
        const float v = (ii < lens[bb]) ? (acc[mi][ni][r] + bv) : 0.f;
        C[(size_t)row * 1024 + col] = v;
      }
    }
  }
}

// ---------------- flash attention, 4 waves/block, 32 i-rows/wave ------------
// R6/R7-proven loop: LDS double-buffered Q/V via global_load_lds, one
// __syncthreads per tile. Load-balanced XCD swizzle bid=[b|hbit|ic|xcd].
// S^T = mfma32(A=Q-frag, B=K-frag): lane l holds col i = l&31,
// row j = (reg&3) + 8*(reg>>2) + 4*(l>>5). Scores in exp2 domain.
__global__ __launch_bounds__(256) void attn_kernel(const u16* __restrict__ Kb, const u16* __restrict__ Qb,
                                                   const u16* __restrict__ Vtb, u16* __restrict__ attb,
                                                   const int* __restrict__ lens) {
  const int bid = blockIdx.x;
  const int b = bid >> 7;
  const int ic = (bid >> 3) & 7;
  const int h = ((bid & 7) << 1) | ((bid >> 6) & 1);
  const int len = lens[b];
  const int i0 = ic * 128;
  if (i0 >= len) return;  // fully-masked rows zeroed by final GEMM
  const int t = threadIdx.x;
  const int w = t >> 6, l = t & 63;
  const int l31 = l & 31, hi = l >> 5;
  const int i0w = i0 + w * 32;

  __shared__ u16 Qs[2][4096];  // 8KB per buffer
  __shared__ u16 Vs[2][4096];

  // K fragments (B operand): col i = l31, k(hd) = ks*16 + hi*8 + e
  short8 kf[4];
  {
    const u16* kp = Kb + ((size_t)(b * NN + i0w + l31)) * DD + h * HD + hi * 8;
#pragma unroll
    for (int ks = 0; ks < 4; ++ks) kf[ks] = *(const short8*)(kp + ks * 16);
  }

  const size_t qsrc = ((size_t)(b * NN) + l31) * DD + h * HD + w * 16 + hi * 8;
  const size_t vsrc = ((size_t)((b * HH + h) * HD + l31)) * NN + w * 16 + hi * 8;

  auto STAGE = [&](int buf, int j0) {
    u16* qd = &Qs[buf][0] + t * 8;
    u16* vd = &Vs[buf][0] + t * 8;
    gld16(Qb + qsrc + (size_t)j0 * DD, qd);
    gld16(Qb + qsrc + (size_t)(j0 + 32) * DD, qd + 2048);
    gld16(Vtb + vsrc + j0, vd);
    gld16(Vtb + vsrc + 32 * NN + j0, vd + 2048);
  };

  f32x16 o0 = zero16(), o1 = zero16();
  float m_run = -3.0e38f, l_run = 0.f;
  const int nt = (len + 63) >> 6;

  STAGE(0, 0);
  __syncthreads();
  for (int jt = 0; jt < nt; ++jt) {
    const int cur = jt & 1;
    const int j0 = jt * 64;
    if (jt + 1 < nt) STAGE(cur ^ 1, j0 + 64);  // async prefetch, drained at end barrier

    const u16* Qc = &Qs[cur][0];
    const u16* Vc = &Vs[cur][0];
    f32x16 s0 = zero16(), s1 = zero16();
    __builtin_amdgcn_s_setprio(1);
#pragma unroll
    for (int ks = 0; ks < 4; ++ks) {
      const short8 qf = *(const short8*)(Qc + (ks * 64 + l) * 8);
      s0 = MFMA32(qf, kf[ks], s0);
    }
#pragma unroll
    for (int ks = 0; ks < 4; ++ks) {
      const short8 qf = *(const short8*)(Qc + ((4 + ks) * 64 + l) * 8);
      s1 = MFMA32(qf, kf[ks], s1);
    }
    __builtin_amdgcn_s_setprio(0);

    if (j0 + 64 > len) {  // uniform; only possible on last tile
#pragma unroll
      for (int r = 0; r < 16; ++r) {
        const int jl = (r & 3) + 8 * (r >> 2) + 4 * hi;
        if (j0 + jl >= len) s0[r] = -3.0e38f;
        if (j0 + 32 + jl >= len) s1[r] = -3.0e38f;
      }
    }

    float pmax = s0[0];
#pragma unroll
    for (int r = 1; r < 16; ++r) pmax = fmaxf(pmax, s0[r]);
#pragma unroll
    for (int r = 0; r < 16; ++r) pmax = fmaxf(pmax, s1[r]);
    pmax = fmaxf(pmax, __shfl_xor(pmax, 32));

    // defer-max (T13): skip O-rescale while tile max within 11.5 (log2) of m_run
    if (!__all(pmax <= m_run + 11.5f)) {
      const float mnew = fmaxf(m_run, pmax);
      const float al = __builtin_amdgcn_exp2f(m_run - mnew);
      l_run *= al;
#pragma unroll
      for (int r = 0; r < 16; ++r) { o0[r] *= al; o1[r] *= al; }
      m_run = mnew;
    }

    float rs = 0.f;
#pragma unroll
    for (int r = 0; r < 16; ++r) { const float p = __builtin_amdgcn_exp2f(s0[r] - m_run); s0[r] = p; rs += p; }
#pragma unroll
    for (int r = 0; r < 16; ++r) { const float p = __builtin_amdgcn_exp2f(s1[r] - m_run); s1[r] = p; rs += p; }
    rs += __shfl_xor(rs, 32);
    l_run += rs;

    // P -> PV B-fragments: per 16-j chunk, 4 cvt_pk + 2 permlane32_swap (T12).
    // v_permlane32_swap_b32 vdst, vsrc: vdst_new = {vdst.lo, vsrc.lo},
    // vsrc_new = {vdst.hi, vsrc.hi}; vdst = low-j word, vsrc = +8 word.
    short8 pf[4];
#pragma unroll
    for (int jk = 0; jk < 4; ++jk) {
      const f32x16& ss = (jk < 2) ? s0 : s1;
      const int kk = jk & 1;
      unsigned W0 = cvtpk(ss[8 * kk + 0], ss[8 * kk + 1]);
      unsigned W1 = cvtpk(ss[8 * kk + 2], ss[8 * kk + 3]);
      unsigned W2 = cvtpk(ss[8 * kk + 4], ss[8 * kk + 5]);
      unsigned W3 = cvtpk(ss[8 * kk + 6], ss[8 * kk + 7]);
      asm("v_permlane32_swap_b32 %0, %1" : "+v"(W0), "+v"(W2));
      asm("v_permlane32_swap_b32 %0, %1" : "+v"(W1), "+v"(W3));
      union { unsigned u[4]; short8 s; } pu;
      pu.u[0] = W0; pu.u[1] = W1; pu.u[2] = W2; pu.u[3] = W3;
      pf[jk] = pu.s;
    }

    __builtin_amdgcn_s_setprio(1);
#pragma unroll
    for (int kkg = 0; kkg < 4; ++kkg) {
      const short8 vf = *(const short8*)(Vc + (kkg * 64 + l) * 8);
      o0 = MFMA32(vf, pf[kkg], o0);
    }
#pragma unroll
    for (int kkg = 0; kkg < 4; ++kkg) {
      const short8 vf = *(const short8*)(Vc + ((4 + kkg) * 64 + l) * 8);
      o1 = MFMA32(vf, pf[kkg], o1);
    }
    __builtin_amdgcn_s_setprio(0);
    __syncthreads();  // drains prefetch (vmcnt) + this tile's ds_reads (lgkm)
  }

  const float inv = 1.f / l_run;
  u16* op = attb + (size_t)(b * NN + i0w + l31) * DD + h * HD + hi * 4;
#pragma unroll
  for (int xs = 0; xs < 2; ++xs) {
    const f32x16& oo = xs ? o1 : o0;
#pragma unroll
    for (int q = 0; q < 4; ++q) {
      short4v st;
#pragma unroll
      for (int e = 0; e < 4; ++e) st[e] = (short)f2bf(oo[q * 4 + e] * inv);
      *(short4v*)(op + xs * 32 + q * 8) = st;
    }
  }
}

// ---------------------------------------------------------------------------
extern "C" void kernel_launch(void* const* d_in, const int* in_sizes, int n_in,
                              void* d_out, int out_size, void* d_ws, size_t ws_size,
                              hipStream_t stream) {
  const float* x = (const float*)d_in[0];
  const unsigned char* mask = (const unsigned char*)d_in[1];
  const float* Wk = (const float*)d_in[2];
  const float* Wq = (const float*)d_in[3];
  const float* Wv = (const float*)d_in[4];
  const float* Wo = (const float*)d_in[5];
  const float* bo = (const float*)d_in[6];
  float* out = (float*)d_out;

  char* ws = (char*)d_ws;
  size_t o = 0;
  int* lens = (int*)(ws + o); o += 256;
  u16* xb  = (u16*)(ws + o); o += (size_t)MM * DD * 2;
  u16* wkb = (u16*)(ws + o); o += (size_t)DD * DD * 2;
  u16* wqb = (u16*)(ws + o); o += (size_t)DD * DD * 2;
  u16* wvb = (u16*)(ws + o); o += (size_t)DD * DD * 2;
  u16* wob = (u16*)(ws + o); o += (size_t)DD * DD * 2;
  u16* kb  = (u16*)(ws + o); o += (size_t)MM * DD * 2;
  u16* qb  = (u16*)(ws + o); o += (size_t)MM * DD * 2;
  u16* vtb = (u16*)(ws + o); o += (size_t)MM * DD * 2;
  u16* attb = xb;  // alias: x only needed until projections finish

  const int xn8 = MM * DD / 8;
  cast_bf16_kernel<<<dim3(xn8 / 256), dim3(256), 0, stream>>>(x, xb, xn8);
  cast4_lens_kernel<<<dim3(DD * DD / 8 / 256, 5), dim3(256), 0, stream>>>(
      Wk, Wq, Wv, Wo, wkb, wqb, wvb, wob, mask, lens);

  gemm_qkv<<<dim3(MM / 128, 24), dim3(256), 0, stream>>>(xb, wkb, wqb, wvb, kb, qb, vtb, lens);

  attn_kernel<<<dim3(1024), dim3(256), 0, stream>>>(kb, qb, vtb, attb, lens);

  gemm_out<<<dim3(MM / 128, DD / 128), dim3(256), 0, stream>>>(attb, wob, out, bo, lens);
}

// Round 10
// 180.539 us; speedup vs baseline: 1.0973x; 1.0193x over previous
//
#include <hip/hip_runtime.h>

typedef unsigned short u16;
typedef __attribute__((ext_vector_type(8))) short short8;
typedef __attribute__((ext_vector_type(4))) short short4v;
typedef __attribute__((ext_vector_type(4))) float f32x4;
typedef __attribute__((ext_vector_type(16))) float f32x16;

#define MFMA16(a, b, c) __builtin_amdgcn_mfma_f32_16x16x32_bf16(a, b, c, 0, 0, 0)
#define MFMA32(a, b, c) __builtin_amdgcn_mfma_f32_32x32x16_bf16(a, b, c, 0, 0, 0)

#define BB 8
#define NN 1024
#define DD 1024
#define HH 16
#define HD 64
#define MM (BB * NN)
// 0.125 (hd^-0.5) * log2(e): softmax computed in exp2 domain
#define SCLOG2 0.18033688011112042f

static __device__ __forceinline__ u16 f2bf(float f) {
  unsigned u = __float_as_uint(f);
  u += 0x7fffu + ((u >> 16) & 1u);  // RNE
  return (u16)(u >> 16);
}

static __device__ __forceinline__ void gld16(const void* g, void* l) {
  __builtin_amdgcn_global_load_lds((const __attribute__((address_space(1))) void*)g,
                                   (__attribute__((address_space(3))) void*)l, 16, 0, 0);
}

static __device__ __forceinline__ unsigned cvtpk(float lo, float hi) {
  unsigned r;
  asm("v_cvt_pk_bf16_f32 %0, %1, %2" : "=v"(r) : "v"(lo), "v"(hi));
  return r;
}

static __device__ __forceinline__ f32x16 zero16() {
  f32x16 v;
#pragma unroll
  for (int i = 0; i < 16; ++i) v[i] = 0.f;
  return v;
}

// ---------------- f32 -> bf16 cast (8 elems/thread) -------------------------
__global__ __launch_bounds__(256) void cast_bf16_kernel(const float* __restrict__ in,
                                                        u16* __restrict__ out, int n8) {
  const int i = blockIdx.x * 256 + threadIdx.x;
  if (i >= n8) return;
  const f32x4* p = (const f32x4*)in + (size_t)i * 2;
  const f32x4 a = p[0], b = p[1];
  short8 o;
  o[0] = (short)f2bf(a[0]); o[1] = (short)f2bf(a[1]);
  o[2] = (short)f2bf(a[2]); o[3] = (short)f2bf(a[3]);
  o[4] = (short)f2bf(b[0]); o[5] = (short)f2bf(b[1]);
  o[6] = (short)f2bf(b[2]); o[7] = (short)f2bf(b[3]);
  *(short8*)(out + (size_t)i * 8) = o;
}

// ------- fused cast of the 4 weight matrices + lens (y==4 plane) ------------
__global__ __launch_bounds__(256) void cast4_lens_kernel(const float* __restrict__ a, const float* __restrict__ b,
                                                         const float* __restrict__ c, const float* __restrict__ d,
                                                         u16* __restrict__ oa, u16* __restrict__ ob,
                                                         u16* __restrict__ oc, u16* __restrict__ od,
                                                         const unsigned char* __restrict__ mask,
                                                         int* __restrict__ lens) {
  if (blockIdx.y == 4) {  // lens plane: only block x==0 works
    if (blockIdx.x != 0) return;
    __shared__ int acc[BB];
    const int t = threadIdx.x;
    if (t < BB) acc[t] = 0;
    __syncthreads();
    const bool isbyte = (mask[1] != 0);  // lengths >= 512 so element 1 is true
    for (int bb = 0; bb < BB; ++bb) {
      int s = 0;
      if (isbyte) {
        for (int i = t; i < NN; i += 256) s += mask[(size_t)bb * NN + i] ? 1 : 0;
      } else {
        const int* mi = (const int*)mask;
        for (int i = t; i < NN; i += 256) s += mi[(size_t)bb * NN + i] != 0 ? 1 : 0;
      }
      if (s) atomicAdd(&acc[bb], s);
    }
    __syncthreads();
    if (t < BB) lens[t] = acc[t];
    return;
  }
  const int i = blockIdx.x * 256 + threadIdx.x;
  const float* in;
  u16* out;
  switch (blockIdx.y) {
    case 0: in = a; out = oa; break;
    case 1: in = b; out = ob; break;
    case 2: in = c; out = oc; break;
    default: in = d; out = od; break;
  }
  const f32x4* p = (const f32x4*)in + (size_t)i * 2;
  const f32x4 va = p[0], vb = p[1];
  short8 o;
  o[0] = (short)f2bf(va[0]); o[1] = (short)f2bf(va[1]);
  o[2] = (short)f2bf(va[2]); o[3] = (short)f2bf(va[3]);
  o[4] = (short)f2bf(vb[0]); o[5] = (short)f2bf(vb[1]);
  o[6] = (short)f2bf(vb[2]); o[7] = (short)f2bf(vb[3]);
  *(short8*)(out + (size_t)i * 8) = o;
}

// ====== GEMM core: 128x128, BK=32, cross-tile dbuf, conflict-free swizzle ===
// (unchanged from R9 — best measured GEMM) byte ^= ((row>>1)&3)<<4 on BOTH
// gld16 source column and ds_read addr; STAGE(next) before compute; one
// __syncthreads per K-step.
#define STAGE_G(d, k0_)                                                            \
  _Pragma("unroll") for (int p = 0; p < 2; ++p) {                                  \
    const int off = (p * 256 + t) * 16;                                            \
    const int row = off >> 6;                                                      \
    const int colb = (off & 63) ^ (((row >> 1) & 3) << 4);                         \
    gld16(Ag + (size_t)(m0 + row) * 1024 + (k0_) + (colb >> 1), &As[d][off >> 1]); \
    gld16(Bg + (size_t)(n0 + row) * 1024 + (k0_) + (colb >> 1), &Bs[d][off >> 1]); \
  }

#define GEMM_CORE2()                                                            \
  STAGE_G(0, 0)                                                                 \
  __syncthreads();                                                              \
  for (int k0 = 0; k0 < 1024; k0 += 32) {                                       \
    const int cur = (k0 >> 5) & 1;                                              \
    if (k0 + 32 < 1024) { STAGE_G(cur ^ 1, k0 + 32) }                           \
    short8 af[4], bf[4];                                                        \
    _Pragma("unroll") for (int mi = 0; mi < 4; ++mi) {                          \
      const int row = wr * 64 + mi * 16 + li;                                   \
      const int byo = row * 64 + ((lg * 16) ^ (((row >> 1) & 3) << 4));         \
      af[mi] = *(const short8*)((const char*)&As[cur][0] + byo);                \
    }                                                                           \
    _Pragma("unroll") for (int ni = 0; ni < 4; ++ni) {                          \
      const int row = wc * 64 + ni * 16 + li;                                   \
      const int byo = row * 64 + ((lg * 16) ^ (((row >> 1) & 3) << 4));         \
      bf[ni] = *(const short8*)((const char*)&Bs[cur][0] + byo);                \
    }                                                                           \
    __builtin_amdgcn_s_setprio(1);                                              \
    _Pragma("unroll") for (int mi = 0; mi < 4; ++mi)                            \
      _Pragma("unroll") for (int ni = 0; ni < 4; ++ni)                          \
          acc[mi][ni] = MFMA16(af[mi], bf[ni], acc[mi][ni]);                    \
    __builtin_amdgcn_s_setprio(0);                                              \
    __syncthreads();                                                            \
  }

// ---------------- fused QKV projection: C_m = xb @ W_m^T, m in {k,q,v} ------
__global__ __launch_bounds__(256) void gemm_qkv(const u16* __restrict__ A,
                                                const u16* __restrict__ Wk3, const u16* __restrict__ Wq3,
                                                const u16* __restrict__ Wv3,
                                                u16* __restrict__ kb, u16* __restrict__ qb,
                                                u16* __restrict__ vtb, const int* __restrict__ lens) {
  const int m0 = blockIdx.x * 128;
  if ((m0 & 1023) >= lens[m0 >> 10]) return;  // dead rows
  __shared__ u16 As[2][4096];
  __shared__ u16 Bs[2][4096];
  const int mat = blockIdx.y >> 3;
  const int n0 = (blockIdx.y & 7) * 128;
  const u16* Ag = A;
  const u16* Bg = (mat == 0) ? Wk3 : (mat == 1) ? Wq3 : Wv3;
  const int t = threadIdx.x;
  const int lane = t & 63;
  const int w = t >> 6;
  const int wr = w >> 1, wc = w & 1;
  const int li = lane & 15, lg = lane >> 4;
  f32x4 acc[4][4] = {};

  GEMM_CORE2()

  if (mat == 2) {  // V: transposed per-head store
#pragma unroll
    for (int mi = 0; mi < 4; ++mi) {
      const int row = m0 + wr * 64 + mi * 16 + lg * 4;  // (b, j)
      const int bb = row >> 10, jj = row & 1023;
#pragma unroll
      for (int ni = 0; ni < 4; ++ni) {
        const int col = n0 + wc * 64 + ni * 16 + li;  // (h, x)
        const int h = col >> 6, x = col & 63;
        short4v st;
#pragma unroll
        for (int r = 0; r < 4; ++r) st[r] = (short)f2bf(acc[mi][ni][r]);
        *(short4v*)(vtb + ((size_t)((bb * HH + h) * HD + x)) * NN + jj) = st;
      }
    }
  } else {
    u16* C = (mat == 0) ? kb : qb;
    const float scale = (mat == 0) ? SCLOG2 : 1.0f;
#pragma unroll
    for (int mi = 0; mi < 4; ++mi)
#pragma unroll
      for (int ni = 0; ni < 4; ++ni) {
        const int col = n0 + wc * 64 + ni * 16 + li;
        const int rowb = m0 + wr * 64 + mi * 16 + lg * 4;
#pragma unroll
        for (int r = 0; r < 4; ++r)
          C[(size_t)(rowb + r) * 1024 + col] = f2bf(acc[mi][ni][r] * scale);
      }
  }
}

// ---------------- output GEMM: out = attb @ Wo^T + bo, mask-zeroed ----------
__global__ __launch_bounds__(256) void gemm_out(const u16* __restrict__ A, const u16* __restrict__ Bw,
                                                float* __restrict__ C, const float* __restrict__ bias,
                                                const int* __restrict__ lens) {
  const int m0 = blockIdx.x * 128;
  const int n0 = blockIdx.y * 128;
  const int t = threadIdx.x;
  if ((m0 & 1023) >= lens[m0 >> 10]) {  // fully-masked tile: store zeros only
    const int r = t >> 1, ch = (t & 1) * 64;
    float* Crow = C + (size_t)(m0 + r) * 1024 + n0 + ch;
    const f32x4 z = {0.f, 0.f, 0.f, 0.f};
#pragma unroll
    for (int c = 0; c < 16; ++c) *(f32x4*)(Crow + c * 4) = z;
    return;
  }
  __shared__ u16 As[2][4096];
  __shared__ u16 Bs[2][4096];
  const u16* Ag = A;
  const u16* Bg = Bw;
  const int lane = t & 63;
  const int w = t >> 6;
  const int wr = w >> 1, wc = w & 1;
  const int li = lane & 15, lg = lane >> 4;
  f32x4 acc[4][4] = {};

  GEMM_CORE2()

#pragma unroll
  for (int ni = 0; ni < 4; ++ni) {
    const int col = n0 + wc * 64 + ni * 16 + li;
    const float bv = bias[col];
#pragma unroll
    for (int mi = 0; mi < 4; ++mi) {
      const int rowb = m0 + wr * 64 + mi * 16 + lg * 4;
#pragma unroll
      for (int r = 0; r < 4; ++r) {
        const int row = rowb + r;
        const int bb = row >> 10, ii = row & 1023;
        const float v = (ii < lens[bb]) ? (acc[mi][ni][r] + bv) : 0.f;
        C[(size_t)row * 1024 + col] = v;
      }
    }
  }
}

// ---------------- flash attention, T15 att[2] pipeline ----------------------
// 4 waves/block, 32 i-rows/wave; LDS dbuf Q/V via global_load_lds (R6-proven
// barrier skeleton). NEW: softmax+PV of tile jt-1 runs DURING QK of tile jt
// (independent register chains -> MFMA pipe and VALU pipe overlap). V-frags
// for tile jt are pre-read into registers in iter jt, consumed by PV in iter
// jt+1 — so every LDS read of a buffer still completes before its closing
// __syncthreads, and the overwriting STAGE happens in the next iter: the
// race-freedom proof of the R6 loop is unchanged.
// S^T = mfma32(A=Q-frag, B=K-frag): lane l holds col i = l&31,
// row j = (reg&3) + 8*(reg>>2) + 4*(l>>5). Scores in exp2 domain (K
// pre-scaled by 0.125*log2e). Load-balanced XCD swizzle bid=[b|hbit|ic|xcd].
#define QK_PART(JC, SN0_, SN1_)                                                \
  { const u16* Qc = &Qs[(JC) & 1][0];                                          \
    SN0_ = zero16(); SN1_ = zero16();                                          \
    __builtin_amdgcn_s_setprio(1);                                             \
    _Pragma("unroll") for (int ks = 0; ks < 4; ++ks) {                         \
      const short8 qf = *(const short8*)(Qc + (ks * 64 + l) * 8);              \
      SN0_ = MFMA32(qf, kf[ks], SN0_); }                                       \
    _Pragma("unroll") for (int ks = 0; ks < 4; ++ks) {                         \
      const short8 qf = *(const short8*)(Qc + ((4 + ks) * 64 + l) * 8);        \
      SN1_ = MFMA32(qf, kf[ks], SN1_); }                                       \
    __builtin_amdgcn_s_setprio(0); }

#define V_READ(JC, VF_)                                                        \
  { const u16* Vc = &Vs[(JC) & 1][0];                                          \
    _Pragma("unroll") for (int kk = 0; kk < 8; ++kk)                           \
      VF_[kk] = *(const short8*)(Vc + (kk * 64 + l) * 8); }

#define SM_PV(S0_, S1_, VF_)                                                   \
  {                                                                            \
    float pmax = S0_[0];                                                       \
    _Pragma("unroll") for (int r = 1; r < 16; ++r) pmax = fmaxf(pmax, S0_[r]); \
    _Pragma("unroll") for (int r = 0; r < 16; ++r) pmax = fmaxf(pmax, S1_[r]); \
    pmax = fmaxf(pmax, __shfl_xor(pmax, 32));                                  \
    if (!__all(pmax <= m_run + 11.5f)) { /* T13 defer-max */                   \
      const float mnew = fmaxf(m_run, pmax);                                   \
      const float al = __builtin_amdgcn_exp2f(m_run - mnew);                   \
      l_run *= al;                                                             \
      _Pragma("unroll") for (int r = 0; r < 16; ++r) { o0[r] *= al; o1[r] *= al; } \
      m_run = mnew;                                                            \
    }                                                                          \
    float rs = 0.f;                                                            \
    _Pragma("unroll") for (int r = 0; r < 16; ++r) {                           \
      const float p = __builtin_amdgcn_exp2f(S0_[r] - m_run); S0_[r] = p; rs += p; } \
    _Pragma("unroll") for (int r = 0; r < 16; ++r) {                           \
      const float p = __builtin_amdgcn_exp2f(S1_[r] - m_run); S1_[r] = p; rs += p; } \
    rs += __shfl_xor(rs, 32);                                                  \
    l_run += rs;                                                               \
    /* T12: cvt_pk + permlane32_swap relayout (verified R3) */                 \
    short8 pf[4];                                                              \
    _Pragma("unroll") for (int jk = 0; jk < 4; ++jk) {                         \
      const f32x16& ss = (jk < 2) ? S0_ : S1_;                                 \
      const int kk2 = jk & 1;                                                  \
      unsigned W0 = cvtpk(ss[8 * kk2 + 0], ss[8 * kk2 + 1]);                   \
      unsigned W1 = cvtpk(ss[8 * kk2 + 2], ss[8 * kk2 + 3]);                   \
      unsigned W2 = cvtpk(ss[8 * kk2 + 4], ss[8 * kk2 + 5]);                   \
      unsigned W3 = cvtpk(ss[8 * kk2 + 6], ss[8 * kk2 + 7]);                   \
      asm("v_permlane32_swap_b32 %0, %1" : "+v"(W0), "+v"(W2));                \
      asm("v_permlane32_swap_b32 %0, %1" : "+v"(W1), "+v"(W3));                \
      union { unsigned u[4]; short8 s; } pu;                                   \
      pu.u[0] = W0; pu.u[1] = W1; pu.u[2] = W2; pu.u[3] = W3;                  \
      pf[jk] = pu.s;                                                           \
    }                                                                          \
    __builtin_amdgcn_s_setprio(1);                                             \
    _Pragma("unroll") for (int kg = 0; kg < 4; ++kg) o0 = MFMA32(VF_[kg], pf[kg], o0); \
    _Pragma("unroll") for (int kg = 0; kg < 4; ++kg) o1 = MFMA32(VF_[4 + kg], pf[kg], o1); \
    __builtin_amdgcn_s_setprio(0);                                             \
  }

#define MASK_LAST(S0_, S1_)                                                    \
  { const int j0m = (nt - 1) * 64;                                             \
    if (j0m + 64 > len) {                                                      \
      _Pragma("unroll") for (int r = 0; r < 16; ++r) {                         \
        const int jl = (r & 3) + 8 * (r >> 2) + 4 * hi;                        \
        if (j0m + jl >= len) S0_[r] = -3.0e38f;                                \
        if (j0m + 32 + jl >= len) S1_[r] = -3.0e38f;                           \
      } } }

#define ATTN_BODY(JT, SP0, SP1, VFP, SN0, SN1, VFN)                            \
  { const int jc = (JT);                                                       \
    if (jc + 1 < nt) STAGE((jc + 1) & 1, (jc + 1) * 64);                       \
    QK_PART(jc, SN0, SN1)                                                      \
    SM_PV(SP0, SP1, VFP)                                                       \
    V_READ(jc, VFN)                                                            \
    __syncthreads(); }

__global__ __launch_bounds__(256) void attn_kernel(const u16* __restrict__ Kb, const u16* __restrict__ Qb,
                                                   const u16* __restrict__ Vtb, u16* __restrict__ attb,
                                                   const int* __restrict__ lens) {
  const int bid = blockIdx.x;
  const int b = bid >> 7;
  const int ic = (bid >> 3) & 7;
  const int h = ((bid & 7) << 1) | ((bid >> 6) & 1);
  const int len = lens[b];
  const int i0 = ic * 128;
  if (i0 >= len) return;  // fully-masked rows zeroed by final GEMM
  const int t = threadIdx.x;
  const int w = t >> 6, l = t & 63;
  const int l31 = l & 31, hi = l >> 5;
  const int i0w = i0 + w * 32;

  __shared__ u16 Qs[2][4096];  // 8KB per buffer
  __shared__ u16 Vs[2][4096];

  // K fragments (B operand): col i = l31, k(hd) = ks*16 + hi*8 + e
  short8 kf[4];
  {
    const u16* kp = Kb + ((size_t)(b * NN + i0w + l31)) * DD + h * HD + hi * 8;
#pragma unroll
    for (int ks = 0; ks < 4; ++ks) kf[ks] = *(const short8*)(kp + ks * 16);
  }

  const size_t qsrc = ((size_t)(b * NN) + l31) * DD + h * HD + w * 16 + hi * 8;
  const size_t vsrc = ((size_t)((b * HH + h) * HD + l31)) * NN + w * 16 + hi * 8;

  auto STAGE = [&](int buf, int j0) {
    u16* qd = &Qs[buf][0] + t * 8;
    u16* vd = &Vs[buf][0] + t * 8;
    gld16(Qb + qsrc + (size_t)j0 * DD, qd);
    gld16(Qb + qsrc + (size_t)(j0 + 32) * DD, qd + 2048);
    gld16(Vtb + vsrc + j0, vd);
    gld16(Vtb + vsrc + 32 * NN + j0, vd + 2048);
  };

  f32x16 o0 = zero16(), o1 = zero16();
  float m_run = -3.0e38f, l_run = 0.f;
  const int nt = (len + 63) >> 6;  // >= 8 since len >= 512

  f32x16 sA0, sA1, sB0, sB1;
  short8 vfA[8], vfB[8];

  STAGE(0, 0);
  __syncthreads();
  if (nt > 1) STAGE(1, 64);
  QK_PART(0, sA0, sA1)
  V_READ(0, vfA)
  __syncthreads();  // drains STAGE(1); all reads of buf0 done before BODY(1)'s STAGE(2)

  int jt = 1;
  for (; jt + 1 < nt; jt += 2) {
    ATTN_BODY(jt, sA0, sA1, vfA, sB0, sB1, vfB)
    ATTN_BODY(jt + 1, sB0, sB1, vfB, sA0, sA1, vfA)
  }
  if (jt < nt) {  // odd remaining body; final tile lands in B
    ATTN_BODY(jt, sA0, sA1, vfA, sB0, sB1, vfB)
    MASK_LAST(sB0, sB1)
    SM_PV(sB0, sB1, vfB)
  } else {  // final tile in A
    MASK_LAST(sA0, sA1)
    SM_PV(sA0, sA1, vfA)
  }

  const float inv = 1.f / l_run;
  u16* op = attb + (size_t)(b * NN + i0w + l31) * DD + h * HD + hi * 4;
#pragma unroll
  for (int xs = 0; xs < 2; ++xs) {
    const f32x16& oo = xs ? o1 : o0;
#pragma unroll
    for (int q = 0; q < 4; ++q) {
      short4v st;
#pragma unroll
      for (int e = 0; e < 4; ++e) st[e] = (short)f2bf(oo[q * 4 + e] * inv);
      *(short4v*)(op + xs * 32 + q * 8) = st;
    }
  }
}

// ---------------------------------------------------------------------------
extern "C" void kernel_launch(void* const* d_in, const int* in_sizes, int n_in,
                              void* d_out, int out_size, void* d_ws, size_t ws_size,
                              hipStream_t stream) {
  const float* x = (const float*)d_in[0];
  const unsigned char* mask = (const unsigned char*)d_in[1];
  const float* Wk = (const float*)d_in[2];
  const float* Wq = (const float*)d_in[3];
  const float* Wv = (const float*)d_in[4];
  const float* Wo = (const float*)d_in[5];
  const float* bo = (const float*)d_in[6];
  float* out = (float*)d_out;

  char* ws = (char*)d_ws;
  size_t o = 0;
  int* lens = (int*)(ws + o); o += 256;
  u16* xb  = (u16*)(ws + o); o += (size_t)MM * DD * 2;
  u16* wkb = (u16*)(ws + o); o += (size_t)DD * DD * 2;
  u16* wqb = (u16*)(ws + o); o += (size_t)DD * DD * 2;
  u16* wvb = (u16*)(ws + o); o += (size_t)DD * DD * 2;
  u16* wob = (u16*)(ws + o); o += (size_t)DD * DD * 2;
  u16* kb  = (u16*)(ws + o); o += (size_t)MM * DD * 2;
  u16* qb  = (u16*)(ws + o); o += (size_t)MM * DD * 2;
  u16* vtb = (u16*)(ws + o); o += (size_t)MM * DD * 2;
  u16* attb = xb;  // alias: x only needed until projections finish

  const int xn8 = MM * DD / 8;
  cast_bf16_kernel<<<dim3(xn8 / 256), dim3(256), 0, stream>>>(x, xb, xn8);
  cast4_lens_kernel<<<dim3(DD * DD / 8 / 256, 5), dim3(256), 0, stream>>>(
      Wk, Wq, Wv, Wo, wkb, wqb, wvb, wob, mask, lens);

  gemm_qkv<<<dim3(MM / 128, 24), dim3(256), 0, stream>>>(xb, wkb, wqb, wvb, kb, qb, vtb, lens);

  attn_kernel<<<dim3(1024), dim3(256), 0, stream>>>(kb, qb, vtb, attb, lens);

  gemm_out<<<dim3(MM / 128, DD / 128), dim3(256), 0, stream>>>(attb, wob, out, bo, lens);
}

// Round 11
// 179.909 us; speedup vs baseline: 1.1011x; 1.0035x over previous
//
#include <hip/hip_runtime.h>

typedef unsigned short u16;
typedef __attribute__((ext_vector_type(8))) short short8;
typedef __attribute__((ext_vector_type(4))) short short4v;
typedef __attribute__((ext_vector_type(4))) float f32x4;
typedef __attribute__((ext_vector_type(16))) float f32x16;

#define MFMA16(a, b, c) __builtin_amdgcn_mfma_f32_16x16x32_bf16(a, b, c, 0, 0, 0)
#define MFMA32(a, b, c) __builtin_amdgcn_mfma_f32_32x32x16_bf16(a, b, c, 0, 0, 0)

#define BB 8
#define NN 1024
#define DD 1024
#define HH 16
#define HD 64
#define MM (BB * NN)
// 0.125 (hd^-0.5) * log2(e): softmax computed in exp2 domain
#define SCLOG2 0.18033688011112042f

#define WAIT_VM(N) asm volatile("s_waitcnt vmcnt(" #N ")" ::: "memory")

static __device__ __forceinline__ u16 f2bf(float f) {
  unsigned u = __float_as_uint(f);
  u += 0x7fffu + ((u >> 16) & 1u);  // RNE
  return (u16)(u >> 16);
}

static __device__ __forceinline__ void gld16(const void* g, void* l) {
  __builtin_amdgcn_global_load_lds((const __attribute__((address_space(1))) void*)g,
                                   (__attribute__((address_space(3))) void*)l, 16, 0, 0);
}

static __device__ __forceinline__ unsigned cvtpk(float lo, float hi) {
  unsigned r;
  asm("v_cvt_pk_bf16_f32 %0, %1, %2" : "=v"(r) : "v"(lo), "v"(hi));
  return r;
}

static __device__ __forceinline__ f32x16 zero16() {
  f32x16 v;
#pragma unroll
  for (int i = 0; i < 16; ++i) v[i] = 0.f;
  return v;
}

// ---------------- f32 -> bf16 cast (8 elems/thread) -------------------------
__global__ __launch_bounds__(256) void cast_bf16_kernel(const float* __restrict__ in,
                                                        u16* __restrict__ out, int n8) {
  const int i = blockIdx.x * 256 + threadIdx.x;
  if (i >= n8) return;
  const f32x4* p = (const f32x4*)in + (size_t)i * 2;
  const f32x4 a = p[0], b = p[1];
  short8 o;
  o[0] = (short)f2bf(a[0]); o[1] = (short)f2bf(a[1]);
  o[2] = (short)f2bf(a[2]); o[3] = (short)f2bf(a[3]);
  o[4] = (short)f2bf(b[0]); o[5] = (short)f2bf(b[1]);
  o[6] = (short)f2bf(b[2]); o[7] = (short)f2bf(b[3]);
  *(short8*)(out + (size_t)i * 8) = o;
}

// ------- fused cast of the 4 weight matrices + lens (y==4 plane) ------------
__global__ __launch_bounds__(256) void cast4_lens_kernel(const float* __restrict__ a, const float* __restrict__ b,
                                                         const float* __restrict__ c, const float* __restrict__ d,
                                                         u16* __restrict__ oa, u16* __restrict__ ob,
                                                         u16* __restrict__ oc, u16* __restrict__ od,
                                                         const unsigned char* __restrict__ mask,
                                                         int* __restrict__ lens) {
  if (blockIdx.y == 4) {  // lens plane: only block x==0 works
    if (blockIdx.x != 0) return;
    __shared__ int acc[BB];
    const int t = threadIdx.x;
    if (t < BB) acc[t] = 0;
    __syncthreads();
    const bool isbyte = (mask[1] != 0);  // lengths >= 512 so element 1 is true
    for (int bb = 0; bb < BB; ++bb) {
      int s = 0;
      if (isbyte) {
        for (int i = t; i < NN; i += 256) s += mask[(size_t)bb * NN + i] ? 1 : 0;
      } else {
        const int* mi = (const int*)mask;
        for (int i = t; i < NN; i += 256) s += mi[(size_t)bb * NN + i] != 0 ? 1 : 0;
      }
      if (s) atomicAdd(&acc[bb], s);
    }
    __syncthreads();
    if (t < BB) lens[t] = acc[t];
    return;
  }
  const int i = blockIdx.x * 256 + threadIdx.x;
  const float* in;
  u16* out;
  switch (blockIdx.y) {
    case 0: in = a; out = oa; break;
    case 1: in = b; out = ob; break;
    case 2: in = c; out = oc; break;
    default: in = d; out = od; break;
  }
  const f32x4* p = (const f32x4*)in + (size_t)i * 2;
  const f32x4 va = p[0], vb = p[1];
  short8 o;
  o[0] = (short)f2bf(va[0]); o[1] = (short)f2bf(va[1]);
  o[2] = (short)f2bf(va[2]); o[3] = (short)f2bf(va[3]);
  o[4] = (short)f2bf(vb[0]); o[5] = (short)f2bf(vb[1]);
  o[6] = (short)f2bf(vb[2]); o[7] = (short)f2bf(vb[3]);
  *(short8*)(out + (size_t)i * 8) = o;
}

// ====== GEMM core v4: 128x128, BK=32, 3-buffer 2-deep prefetch + T4 ========
// Per K-step kt:
//   fence; B_top   — closes last iter's reads of buf[(kt+2)%3] (= (kt-1)%3)
//   STAGE(kt+2 -> buf[(kt+2)%3])  — overwrite is now safe
//   vmcnt(8)       — waits ONLY stage(kt) (issued 2 iters ~500+ cyc ago);
//                    the 8 newer loads stay in flight across the barrier
//   B_mid; fence   — buf[kt%3] complete across ALL waves
//   ds_read (conflict-free swizzle) + 16 MFMA
// No vmcnt(0) drain in the loop (T4); no sched_barrier(0) pinning (R8/m141).
// Swizzle byte ^= ((row>>1)&3)<<4 on BOTH gld16 source col and ds_read addr
// (involution; LDS dest linear per rule 21; R8-verified 0 conflicts).
#define STAGE_B(d, k0_)                                                            \
  _Pragma("unroll") for (int p = 0; p < 2; ++p) {                                  \
    const int off = (p * 256 + t) * 16;                                            \
    const int row = off >> 6;                                                      \
    const int colb = (off & 63) ^ (((row >> 1) & 3) << 4);                         \
    gld16(Ag + (size_t)(m0 + row) * 1024 + (k0_) + (colb >> 1), &As[d][off >> 1]); \
    gld16(Bg + (size_t)(n0 + row) * 1024 + (k0_) + (colb >> 1), &Bs[d][off >> 1]); \
  }

#define GEMM_CORE4()                                                            \
  STAGE_B(0, 0)                                                                 \
  STAGE_B(1, 32)                                                                \
  _Pragma("unroll") for (int kt = 0; kt < 32; ++kt) {                           \
    asm volatile("" ::: "memory");                                              \
    __builtin_amdgcn_s_barrier(); /* B_top */                                   \
    if (kt < 30) {                                                              \
      const int bn = (kt + 2) % 3;                                              \
      STAGE_B(bn, (kt + 2) * 32)                                                \
      WAIT_VM(8);                                                               \
    } else if (kt == 30) {                                                      \
      WAIT_VM(4);                                                               \
    } else {                                                                    \
      WAIT_VM(0);                                                               \
    }                                                                           \
    __builtin_amdgcn_s_barrier(); /* B_mid */                                   \
    asm volatile("" ::: "memory");                                              \
    const int bc = kt % 3;                                                      \
    short8 af[4], bf[4];                                                        \
    _Pragma("unroll") for (int mi = 0; mi < 4; ++mi) {                          \
      const int row = wr * 64 + mi * 16 + li;                                   \
      const int byo = row * 64 + ((lg * 16) ^ (((row >> 1) & 3) << 4));         \
      af[mi] = *(const short8*)((const char*)&As[bc][0] + byo);                 \
    }                                                                           \
    _Pragma("unroll") for (int ni = 0; ni < 4; ++ni) {                          \
      const int row = wc * 64 + ni * 16 + li;                                   \
      const int byo = row * 64 + ((lg * 16) ^ (((row >> 1) & 3) << 4));         \
      bf[ni] = *(const short8*)((const char*)&Bs[bc][0] + byo);                 \
    }                                                                           \
    __builtin_amdgcn_s_setprio(1);                                              \
    _Pragma("unroll") for (int mi = 0; mi < 4; ++mi)                            \
      _Pragma("unroll") for (int ni = 0; ni < 4; ++ni)                          \
          acc[mi][ni] = MFMA16(af[mi], bf[ni], acc[mi][ni]);                    \
    __builtin_amdgcn_s_setprio(0);                                              \
  }

// ---------------- fused QKV projection: C_m = xb @ W_m^T, m in {k,q,v} ------
__global__ __launch_bounds__(256) void gemm_qkv(const u16* __restrict__ A,
                                                const u16* __restrict__ Wk3, const u16* __restrict__ Wq3,
                                                const u16* __restrict__ Wv3,
                                                u16* __restrict__ kb, u16* __restrict__ qb,
                                                u16* __restrict__ vtb, const int* __restrict__ lens) {
  const int m0 = blockIdx.x * 128;
  if ((m0 & 1023) >= lens[m0 >> 10]) return;  // dead rows
  __shared__ u16 As[3][4096];
  __shared__ u16 Bs[3][4096];
  const int mat = blockIdx.y >> 3;
  const int n0 = (blockIdx.y & 7) * 128;
  const u16* Ag = A;
  const u16* Bg = (mat == 0) ? Wk3 : (mat == 1) ? Wq3 : Wv3;
  const int t = threadIdx.x;
  const int lane = t & 63;
  const int w = t >> 6;
  const int wr = w >> 1, wc = w & 1;
  const int li = lane & 15, lg = lane >> 4;
  f32x4 acc[4][4] = {};

  GEMM_CORE4()

  if (mat == 2) {  // V: transposed per-head store
#pragma unroll
    for (int mi = 0; mi < 4; ++mi) {
      const int row = m0 + wr * 64 + mi * 16 + lg * 4;  // (b, j)
      const int bb = row >> 10, jj = row & 1023;
#pragma unroll
      for (int ni = 0; ni < 4; ++ni) {
        const int col = n0 + wc * 64 + ni * 16 + li;  // (h, x)
        const int h = col >> 6, x = col & 63;
        short4v st;
#pragma unroll
        for (int r = 0; r < 4; ++r) st[r] = (short)f2bf(acc[mi][ni][r]);
        *(short4v*)(vtb + ((size_t)((bb * HH + h) * HD + x)) * NN + jj) = st;
      }
    }
  } else {
    u16* C = (mat == 0) ? kb : qb;
    const float scale = (mat == 0) ? SCLOG2 : 1.0f;
#pragma unroll
    for (int mi = 0; mi < 4; ++mi)
#pragma unroll
      for (int ni = 0; ni < 4; ++ni) {
        const int col = n0 + wc * 64 + ni * 16 + li;
        const int rowb = m0 + wr * 64 + mi * 16 + lg * 4;
#pragma unroll
        for (int r = 0; r < 4; ++r)
          C[(size_t)(rowb + r) * 1024 + col] = f2bf(acc[mi][ni][r] * scale);
      }
  }
}

// ---------------- output GEMM: out = attb @ Wo^T + bo, mask-zeroed ----------
__global__ __launch_bounds__(256) void gemm_out(const u16* __restrict__ A, const u16* __restrict__ Bw,
                                                float* __restrict__ C, const float* __restrict__ bias,
                                                const int* __restrict__ lens) {
  const int m0 = blockIdx.x * 128;
  const int n0 = blockIdx.y * 128;
  const int t = threadIdx.x;
  if ((m0 & 1023) >= lens[m0 >> 10]) {  // fully-masked tile: store zeros only
    const int r = t >> 1, ch = (t & 1) * 64;
    float* Crow = C + (size_t)(m0 + r) * 1024 + n0 + ch;
    const f32x4 z = {0.f, 0.f, 0.f, 0.f};
#pragma unroll
    for (int c = 0; c < 16; ++c) *(f32x4*)(Crow + c * 4) = z;
    return;
  }
  __shared__ u16 As[3][4096];
  __shared__ u16 Bs[3][4096];
  const u16* Ag = A;
  const u16* Bg = Bw;
  const int lane = t & 63;
  const int w = t >> 6;
  const int wr = w >> 1, wc = w & 1;
  const int li = lane & 15, lg = lane >> 4;
  f32x4 acc[4][4] = {};

  GEMM_CORE4()

#pragma unroll
  for (int ni = 0; ni < 4; ++ni) {
    const int col = n0 + wc * 64 + ni * 16 + li;
    const float bv = bias[col];
#pragma unroll
    for (int mi = 0; mi < 4; ++mi) {
      const int rowb = m0 + wr * 64 + mi * 16 + lg * 4;
#pragma unroll
      for (int r = 0; r < 4; ++r) {
        const int row = rowb + r;
        const int bb = row >> 10, ii = row & 1023;
        const float v = (ii < lens[bb]) ? (acc[mi][ni][r] + bv) : 0.f;
        C[(size_t)row * 1024 + col] = v;
      }
    }
  }
}

// ---------------- flash attention, T15 att[2] pipeline (unchanged R10) ------
#define QK_PART(JC, SN0_, SN1_)                                                \
  { const u16* Qc = &Qs[(JC) & 1][0];                                          \
    SN0_ = zero16(); SN1_ = zero16();                                          \
    __builtin_amdgcn_s_setprio(1);                                             \
    _Pragma("unroll") for (int ks = 0; ks < 4; ++ks) {                         \
      const short8 qf = *(const short8*)(Qc + (ks * 64 + l) * 8);              \
      SN0_ = MFMA32(qf, kf[ks], SN0_); }                                       \
    _Pragma("unroll") for (int ks = 0; ks < 4; ++ks) {                         \
      const short8 qf = *(const short8*)(Qc + ((4 + ks) * 64 + l) * 8);        \
      SN1_ = MFMA32(qf, kf[ks], SN1_); }                                       \
    __builtin_amdgcn_s_setprio(0); }

#define V_READ(JC, VF_)                                                        \
  { const u16* Vc = &Vs[(JC) & 1][0];                                          \
    _Pragma("unroll") for (int kk = 0; kk < 8; ++kk)                           \
      VF_[kk] = *(const short8*)(Vc + (kk * 64 + l) * 8); }

#define SM_PV(S0_, S1_, VF_)                                                   \
  {                                                                            \
    float pmax = S0_[0];                                                       \
    _Pragma("unroll") for (int r = 1; r < 16; ++r) pmax = fmaxf(pmax, S0_[r]); \
    _Pragma("unroll") for (int r = 0; r < 16; ++r) pmax = fmaxf(pmax, S1_[r]); \
    pmax = fmaxf(pmax, __shfl_xor(pmax, 32));                                  \
    if (!__all(pmax <= m_run + 11.5f)) { /* T13 defer-max */                   \
      const float mnew = fmaxf(m_run, pmax);                                   \
      const float al = __builtin_amdgcn_exp2f(m_run - mnew);                   \
      l_run *= al;                                                             \
      _Pragma("unroll") for (int r = 0; r < 16; ++r) { o0[r] *= al; o1[r] *= al; } \
      m_run = mnew;                                                            \
    }                                                                          \
    float rs = 0.f;                                                            \
    _Pragma("unroll") for (int r = 0; r < 16; ++r) {                           \
      const float p = __builtin_amdgcn_exp2f(S0_[r] - m_run); S0_[r] = p; rs += p; } \
    _Pragma("unroll") for (int r = 0; r < 16; ++r) {                           \
      const float p = __builtin_amdgcn_exp2f(S1_[r] - m_run); S1_[r] = p; rs += p; } \
    rs += __shfl_xor(rs, 32);                                                  \
    l_run += rs;                                                               \
    short8 pf[4];                                                              \
    _Pragma("unroll") for (int jk = 0; jk < 4; ++jk) {                         \
      const f32x16& ss = (jk < 2) ? S0_ : S1_;                                 \
      const int kk2 = jk & 1;                                                  \
      unsigned W0 = cvtpk(ss[8 * kk2 + 0], ss[8 * kk2 + 1]);                   \
      unsigned W1 = cvtpk(ss[8 * kk2 + 2], ss[8 * kk2 + 3]);                   \
      unsigned W2 = cvtpk(ss[8 * kk2 + 4], ss[8 * kk2 + 5]);                   \
      unsigned W3 = cvtpk(ss[8 * kk2 + 6], ss[8 * kk2 + 7]);                   \
      asm("v_permlane32_swap_b32 %0, %1" : "+v"(W0), "+v"(W2));                \
      asm("v_permlane32_swap_b32 %0, %1" : "+v"(W1), "+v"(W3));                \
      union { unsigned u[4]; short8 s; } pu;                                   \
      pu.u[0] = W0; pu.u[1] = W1; pu.u[2] = W2; pu.u[3] = W3;                  \
      pf[jk] = pu.s;                                                           \
    }                                                                          \
    __builtin_amdgcn_s_setprio(1);                                             \
    _Pragma("unroll") for (int kg = 0; kg < 4; ++kg) o0 = MFMA32(VF_[kg], pf[kg], o0); \
    _Pragma("unroll") for (int kg = 0; kg < 4; ++kg) o1 = MFMA32(VF_[4 + kg], pf[kg], o1); \
    __builtin_amdgcn_s_setprio(0);                                             \
  }

#define MASK_LAST(S0_, S1_)                                                    \
  { const int j0m = (nt - 1) * 64;                                             \
    if (j0m + 64 > len) {                                                      \
      _Pragma("unroll") for (int r = 0; r < 16; ++r) {                         \
        const int jl = (r & 3) + 8 * (r >> 2) + 4 * hi;                        \
        if (j0m + jl >= len) S0_[r] = -3.0e38f;                                \
        if (j0m + 32 + jl >= len) S1_[r] = -3.0e38f;                           \
      } } }

#define ATTN_BODY(JT, SP0, SP1, VFP, SN0, SN1, VFN)                            \
  { const int jc = (JT);                                                       \
    if (jc + 1 < nt) STAGE((jc + 1) & 1, (jc + 1) * 64);                       \
    QK_PART(jc, SN0, SN1)                                                      \
    SM_PV(SP0, SP1, VFP)                                                       \
    V_READ(jc, VFN)                                                            \
    __syncthreads(); }

__global__ __launch_bounds__(256) void attn_kernel(const u16* __restrict__ Kb, const u16* __restrict__ Qb,
                                                   const u16* __restrict__ Vtb, u16* __restrict__ attb,
                                                   const int* __restrict__ lens) {
  const int bid = blockIdx.x;
  const int b = bid >> 7;
  const int ic = (bid >> 3) & 7;
  const int h = ((bid & 7) << 1) | ((bid >> 6) & 1);
  const int len = lens[b];
  const int i0 = ic * 128;
  if (i0 >= len) return;  // fully-masked rows zeroed by final GEMM
  const int t = threadIdx.x;
  const int w = t >> 6, l = t & 63;
  const int l31 = l & 31, hi = l >> 5;
  const int i0w = i0 + w * 32;

  __shared__ u16 Qs[2][4096];  // 8KB per buffer
  __shared__ u16 Vs[2][4096];

  short8 kf[4];
  {
    const u16* kp = Kb + ((size_t)(b * NN + i0w + l31)) * DD + h * HD + hi * 8;
#pragma unroll
    for (int ks = 0; ks < 4; ++ks) kf[ks] = *(const short8*)(kp + ks * 16);
  }

  const size_t qsrc = ((size_t)(b * NN) + l31) * DD + h * HD + w * 16 + hi * 8;
  const size_t vsrc = ((size_t)((b * HH + h) * HD + l31)) * NN + w * 16 + hi * 8;

  auto STAGE = [&](int buf, int j0) {
    u16* qd = &Qs[buf][0] + t * 8;
    u16* vd = &Vs[buf][0] + t * 8;
    gld16(Qb + qsrc + (size_t)j0 * DD, qd);
    gld16(Qb + qsrc + (size_t)(j0 + 32) * DD, qd + 2048);
    gld16(Vtb + vsrc + j0, vd);
    gld16(Vtb + vsrc + 32 * NN + j0, vd + 2048);
  };

  f32x16 o0 = zero16(), o1 = zero16();
  float m_run = -3.0e38f, l_run = 0.f;
  const int nt = (len + 63) >> 6;  // >= 8 since len >= 512

  f32x16 sA0, sA1, sB0, sB1;
  short8 vfA[8], vfB[8];

  STAGE(0, 0);
  __syncthreads();
  if (nt > 1) STAGE(1, 64);
  QK_PART(0, sA0, sA1)
  V_READ(0, vfA)
  __syncthreads();

  int jt = 1;
  for (; jt + 1 < nt; jt += 2) {
    ATTN_BODY(jt, sA0, sA1, vfA, sB0, sB1, vfB)
    ATTN_BODY(jt + 1, sB0, sB1, vfB, sA0, sA1, vfA)
  }
  if (jt < nt) {
    ATTN_BODY(jt, sA0, sA1, vfA, sB0, sB1, vfB)
    MASK_LAST(sB0, sB1)
    SM_PV(sB0, sB1, vfB)
  } else {
    MASK_LAST(sA0, sA1)
    SM_PV(sA0, sA1, vfA)
  }

  const float inv = 1.f / l_run;
  u16* op = attb + (size_t)(b * NN + i0w + l31) * DD + h * HD + hi * 4;
#pragma unroll
  for (int xs = 0; xs < 2; ++xs) {
    const f32x16& oo = xs ? o1 : o0;
#pragma unroll
    for (int q = 0; q < 4; ++q) {
      short4v st;
#pragma unroll
      for (int e = 0; e < 4; ++e) st[e] = (short)f2bf(oo[q * 4 + e] * inv);
      *(short4v*)(op + xs * 32 + q * 8) = st;
    }
  }
}

// ---------------------------------------------------------------------------
extern "C" void kernel_launch(void* const* d_in, const int* in_sizes, int n_in,
                              void* d_out, int out_size, void* d_ws, size_t ws_size,
                              hipStream_t stream) {
  const float* x = (const float*)d_in[0];
  const unsigned char* mask = (const unsigned char*)d_in[1];
  const float* Wk = (const float*)d_in[2];
  const float* Wq = (const float*)d_in[3];
  const float* Wv = (const float*)d_in[4];
  const float* Wo = (const float*)d_in[5];
  const float* bo = (const float*)d_in[6];
  float* out = (float*)d_out;

  char* ws = (char*)d_ws;
  size_t o = 0;
  int* lens = (int*)(ws + o); o += 256;
  u16* xb  = (u16*)(ws + o); o += (size_t)MM * DD * 2;
  u16* wkb = (u16*)(ws + o); o += (size_t)DD * DD * 2;
  u16* wqb = (u16*)(ws + o); o += (size_t)DD * DD * 2;
  u16* wvb = (u16*)(ws + o); o += (size_t)DD * DD * 2;
  u16* wob = (u16*)(ws + o); o += (size_t)DD * DD * 2;
  u16* kb  = (u16*)(ws + o); o += (size_t)MM * DD * 2;
  u16* qb  = (u16*)(ws + o); o += (size_t)MM * DD * 2;
  u16* vtb = (u16*)(ws + o); o += (size_t)MM * DD * 2;
  u16* attb = xb;  // alias: x only needed until projections finish

  const int xn8 = MM * DD / 8;
  cast_bf16_kernel<<<dim3(xn8 / 256), dim3(256), 0, stream>>>(x, xb, xn8);
  cast4_lens_kernel<<<dim3(DD * DD / 8 / 256, 5), dim3(256), 0, stream>>>(
      Wk, Wq, Wv, Wo, wkb, wqb, wvb, wob, mask, lens);

  gemm_qkv<<<dim3(MM / 128, 24), dim3(256), 0, stream>>>(xb, wkb, wqb, wvb, kb, qb, vtb, lens);

  attn_kernel<<<dim3(1024), dim3(256), 0, stream>>>(kb, qb, vtb, attb, lens);

  gemm_out<<<dim3(MM / 128, DD / 128), dim3(256), 0, stream>>>(attb, wob, out, bo, lens);
}

// Round 12
// 177.605 us; speedup vs baseline: 1.1154x; 1.0130x over previous
//
#include <hip/hip_runtime.h>

typedef unsigned short u16;
typedef __attribute__((ext_vector_type(8))) short short8;
typedef __attribute__((ext_vector_type(4))) short short4v;
typedef __attribute__((ext_vector_type(4))) float f32x4;
typedef __attribute__((ext_vector_type(16))) float f32x16;

#define MFMA16(a, b, c) __builtin_amdgcn_mfma_f32_16x16x32_bf16(a, b, c, 0, 0, 0)
#define MFMA32(a, b, c) __builtin_amdgcn_mfma_f32_32x32x16_bf16(a, b, c, 0, 0, 0)

#define BB 8
#define NN 1024
#define DD 1024
#define HH 16
#define HD 64
#define MM (BB * NN)
// 0.125 (hd^-0.5) * log2(e): softmax computed in exp2 domain
#define SCLOG2 0.18033688011112042f

static __device__ __forceinline__ u16 f2bf(float f) {
  unsigned u = __float_as_uint(f);
  u += 0x7fffu + ((u >> 16) & 1u);  // RNE
  return (u16)(u >> 16);
}

static __device__ __forceinline__ void gld16(const void* g, void* l) {
  __builtin_amdgcn_global_load_lds((const __attribute__((address_space(1))) void*)g,
                                   (__attribute__((address_space(3))) void*)l, 16, 0, 0);
}

static __device__ __forceinline__ unsigned cvtpk(float lo, float hi) {
  unsigned r;
  asm("v_cvt_pk_bf16_f32 %0, %1, %2" : "=v"(r) : "v"(lo), "v"(hi));
  return r;
}

static __device__ __forceinline__ f32x16 zero16() {
  f32x16 v;
#pragma unroll
  for (int i = 0; i < 16; ++i) v[i] = 0.f;
  return v;
}

// ---- merged prep kernel: x-cast (blocks 0..4095), 4 weight casts
// (4096..6143), lens (6144) -----------------------------------------------
__global__ __launch_bounds__(256) void prep_kernel(const float* __restrict__ x,
                                                   const float* __restrict__ Wk, const float* __restrict__ Wq,
                                                   const float* __restrict__ Wv, const float* __restrict__ Wo,
                                                   u16* __restrict__ xb,
                                                   u16* __restrict__ wkb, u16* __restrict__ wqb,
                                                   u16* __restrict__ wvb, u16* __restrict__ wob,
                                                   const unsigned char* __restrict__ mask,
                                                   int* __restrict__ lens) {
  const int bid = blockIdx.x;
  const int t = threadIdx.x;
  if (bid == 6144) {  // lens
    __shared__ int acc[BB];
    if (t < BB) acc[t] = 0;
    __syncthreads();
    const bool isbyte = (mask[1] != 0);  // lengths >= 512 so element 1 is true
    for (int bb = 0; bb < BB; ++bb) {
      int s = 0;
      if (isbyte) {
        for (int i = t; i < NN; i += 256) s += mask[(size_t)bb * NN + i] ? 1 : 0;
      } else {
        const int* mi = (const int*)mask;
        for (int i = t; i < NN; i += 256) s += mi[(size_t)bb * NN + i] != 0 ? 1 : 0;
      }
      if (s) atomicAdd(&acc[bb], s);
    }
    __syncthreads();
    if (t < BB) lens[t] = acc[t];
    return;
  }
  const float* in;
  u16* out;
  int i;
  if (bid < 4096) {
    in = x; out = xb; i = bid * 256 + t;
  } else {
    const int wi = bid - 4096;
    const int mat = wi >> 9;  // 512 blocks per matrix
    switch (mat) {
      case 0: in = Wk; out = wkb; break;
      case 1: in = Wq; out = wqb; break;
      case 2: in = Wv; out = wvb; break;
      default: in = Wo; out = wob; break;
    }
    i = (wi & 511) * 256 + t;
  }
  const f32x4* p = (const f32x4*)in + (size_t)i * 2;
  const f32x4 a = p[0], b = p[1];
  short8 o;
  o[0] = (short)f2bf(a[0]); o[1] = (short)f2bf(a[1]);
  o[2] = (short)f2bf(a[2]); o[3] = (short)f2bf(a[3]);
  o[4] = (short)f2bf(b[0]); o[5] = (short)f2bf(b[1]);
  o[6] = (short)f2bf(b[2]); o[7] = (short)f2bf(b[3]);
  *(short8*)(out + (size_t)i * 8) = o;
}

// ====== GEMM core: 128x128, BK=32, cross-tile dbuf, conflict-free swizzle ===
// (R9 exact — best measured GEMM) byte ^= ((row>>1)&3)<<4 on BOTH gld16
// source column and ds_read addr; STAGE(next) before compute; one
// __syncthreads per K-step. Four scheduling variants (R6-R11) all land at
// MfmaUtil ~21% — this is the 128²-structure shape ceiling for K=1024.
#define STAGE_G(d, k0_)                                                            \
  _Pragma("unroll") for (int p = 0; p < 2; ++p) {                                  \
    const int off = (p * 256 + t) * 16;                                            \
    const int row = off >> 6;                                                      \
    const int colb = (off & 63) ^ (((row >> 1) & 3) << 4);                         \
    gld16(Ag + (size_t)(m0 + row) * 1024 + (k0_) + (colb >> 1), &As[d][off >> 1]); \
    gld16(Bg + (size_t)(n0 + row) * 1024 + (k0_) + (colb >> 1), &Bs[d][off >> 1]); \
  }

#define GEMM_CORE2()                                                            \
  STAGE_G(0, 0)                                                                 \
  __syncthreads();                                                              \
  for (int k0 = 0; k0 < 1024; k0 += 32) {                                       \
    const int cur = (k0 >> 5) & 1;                                              \
    if (k0 + 32 < 1024) { STAGE_G(cur ^ 1, k0 + 32) }                           \
    short8 af[4], bf[4];                                                        \
    _Pragma("unroll") for (int mi = 0; mi < 4; ++mi) {                          \
      const int row = wr * 64 + mi * 16 + li;                                   \
      const int byo = row * 64 + ((lg * 16) ^ (((row >> 1) & 3) << 4));         \
      af[mi] = *(const short8*)((const char*)&As[cur][0] + byo);                \
    }                                                                           \
    _Pragma("unroll") for (int ni = 0; ni < 4; ++ni) {                          \
      const int row = wc * 64 + ni * 16 + li;                                   \
      const int byo = row * 64 + ((lg * 16) ^ (((row >> 1) & 3) << 4));         \
      bf[ni] = *(const short8*)((const char*)&Bs[cur][0] + byo);                \
    }                                                                           \
    __builtin_amdgcn_s_setprio(1);                                              \
    _Pragma("unroll") for (int mi = 0; mi < 4; ++mi)                            \
      _Pragma("unroll") for (int ni = 0; ni < 4; ++ni)                          \
          acc[mi][ni] = MFMA16(af[mi], bf[ni], acc[mi][ni]);                    \
    __builtin_amdgcn_s_setprio(0);                                              \
    __syncthreads();                                                            \
  }

// ---------------- fused QKV projection: C_m = xb @ W_m^T, m in {k,q,v} ------
__global__ __launch_bounds__(256) void gemm_qkv(const u16* __restrict__ A,
                                                const u16* __restrict__ Wk3, const u16* __restrict__ Wq3,
                                                const u16* __restrict__ Wv3,
                                                u16* __restrict__ kb, u16* __restrict__ qb,
                                                u16* __restrict__ vtb, const int* __restrict__ lens) {
  const int m0 = blockIdx.x * 128;
  if ((m0 & 1023) >= lens[m0 >> 10]) return;  // dead rows
  __shared__ u16 As[2][4096];
  __shared__ u16 Bs[2][4096];
  const int mat = blockIdx.y >> 3;
  const int n0 = (blockIdx.y & 7) * 128;
  const u16* Ag = A;
  const u16* Bg = (mat == 0) ? Wk3 : (mat == 1) ? Wq3 : Wv3;
  const int t = threadIdx.x;
  const int lane = t & 63;
  const int w = t >> 6;
  const int wr = w >> 1, wc = w & 1;
  const int li = lane & 15, lg = lane >> 4;
  f32x4 acc[4][4] = {};

  GEMM_CORE2()

  if (mat == 2) {  // V: transposed per-head store
#pragma unroll
    for (int mi = 0; mi < 4; ++mi) {
      const int row = m0 + wr * 64 + mi * 16 + lg * 4;  // (b, j)
      const int bb = row >> 10, jj = row & 1023;
#pragma unroll
      for (int ni = 0; ni < 4; ++ni) {
        const int col = n0 + wc * 64 + ni * 16 + li;  // (h, x)
        const int h = col >> 6, x = col & 63;
        short4v st;
#pragma unroll
        for (int r = 0; r < 4; ++r) st[r] = (short)f2bf(acc[mi][ni][r]);
        *(short4v*)(vtb + ((size_t)((bb * HH + h) * HD + x)) * NN + jj) = st;
      }
    }
  } else {
    u16* C = (mat == 0) ? kb : qb;
    const float scale = (mat == 0) ? SCLOG2 : 1.0f;
#pragma unroll
    for (int mi = 0; mi < 4; ++mi)
#pragma unroll
      for (int ni = 0; ni < 4; ++ni) {
        const int col = n0 + wc * 64 + ni * 16 + li;
        const int rowb = m0 + wr * 64 + mi * 16 + lg * 4;
#pragma unroll
        for (int r = 0; r < 4; ++r)
          C[(size_t)(rowb + r) * 1024 + col] = f2bf(acc[mi][ni][r] * scale);
      }
  }
}

// ---------------- output GEMM: out = attb @ Wo^T + bo, mask-zeroed ----------
__global__ __launch_bounds__(256) void gemm_out(const u16* __restrict__ A, const u16* __restrict__ Bw,
                                                float* __restrict__ C, const float* __restrict__ bias,
                                                const int* __restrict__ lens) {
  const int m0 = blockIdx.x * 128;
  const int n0 = blockIdx.y * 128;
  const int t = threadIdx.x;
  if ((m0 & 1023) >= lens[m0 >> 10]) {  // fully-masked tile: store zeros only
    const int r = t >> 1, ch = (t & 1) * 64;
    float* Crow = C + (size_t)(m0 + r) * 1024 + n0 + ch;
    const f32x4 z = {0.f, 0.f, 0.f, 0.f};
#pragma unroll
    for (int c = 0; c < 16; ++c) *(f32x4*)(Crow + c * 4) = z;
    return;
  }
  __shared__ u16 As[2][4096];
  __shared__ u16 Bs[2][4096];
  const u16* Ag = A;
  const u16* Bg = Bw;
  const int lane = t & 63;
  const int w = t >> 6;
  const int wr = w >> 1, wc = w & 1;
  const int li = lane & 15, lg = lane >> 4;
  f32x4 acc[4][4] = {};

  GEMM_CORE2()

#pragma unroll
  for (int ni = 0; ni < 4; ++ni) {
    const int col = n0 + wc * 64 + ni * 16 + li;
    const float bv = bias[col];
#pragma unroll
    for (int mi = 0; mi < 4; ++mi) {
      const int rowb = m0 + wr * 64 + mi * 16 + lg * 4;
#pragma unroll
      for (int r = 0; r < 4; ++r) {
        const int row = rowb + r;
        const int bb = row >> 10, ii = row & 1023;
        const float v = (ii < lens[bb]) ? (acc[mi][ni][r] + bv) : 0.f;
        C[(size_t)row * 1024 + col] = v;
      }
    }
  }
}

// ---------------- flash attention, T15 att[2] pipeline + tree reductions ----
// Structure identical to R10/R11 (best measured). NEW: the two serial 31-op
// reduction chains (pmax fmax-chain, rs add-chain; IEEE order blocks compiler
// reassociation) replaced by balanced trees (depth ~5) and 4-way partial
// sums — cuts ~250 dependent cycles per tile on the latency-bound chain.
#define QK_PART(JC, SN0_, SN1_)                                                \
  { const u16* Qc = &Qs[(JC) & 1][0];                                          \
    SN0_ = zero16(); SN1_ = zero16();                                          \
    __builtin_amdgcn_s_setprio(1);                                             \
    _Pragma("unroll") for (int ks = 0; ks < 4; ++ks) {                         \
      const short8 qf = *(const short8*)(Qc + (ks * 64 + l) * 8);              \
      SN0_ = MFMA32(qf, kf[ks], SN0_); }                                       \
    _Pragma("unroll") for (int ks = 0; ks < 4; ++ks) {                         \
      const short8 qf = *(const short8*)(Qc + ((4 + ks) * 64 + l) * 8);        \
      SN1_ = MFMA32(qf, kf[ks], SN1_); }                                       \
    __builtin_amdgcn_s_setprio(0); }

#define V_READ(JC, VF_)                                                        \
  { const u16* Vc = &Vs[(JC) & 1][0];                                          \
    _Pragma("unroll") for (int kk = 0; kk < 8; ++kk)                           \
      VF_[kk] = *(const short8*)(Vc + (kk * 64 + l) * 8); }

#define SM_PV(S0_, S1_, VF_)                                                   \
  {                                                                            \
    float tmx[8];                                                              \
    _Pragma("unroll") for (int r = 0; r < 8; ++r)                              \
      tmx[r] = fmaxf(fmaxf(S0_[r], S0_[r + 8]), fmaxf(S1_[r], S1_[r + 8]));    \
    _Pragma("unroll") for (int r = 0; r < 4; ++r)                              \
      tmx[r] = fmaxf(tmx[r], tmx[r + 4]);                                      \
    float pmax = fmaxf(fmaxf(tmx[0], tmx[1]), fmaxf(tmx[2], tmx[3]));          \
    pmax = fmaxf(pmax, __shfl_xor(pmax, 32));                                  \
    if (!__all(pmax <= m_run + 11.5f)) { /* T13 defer-max */                   \
      const float mnew = fmaxf(m_run, pmax);                                   \
      const float al = __builtin_amdgcn_exp2f(m_run - mnew);                   \
      l_run *= al;                                                             \
      _Pragma("unroll") for (int r = 0; r < 16; ++r) { o0[r] *= al; o1[r] *= al; } \
      m_run = mnew;                                                            \
    }                                                                          \
    float ac0 = 0.f, ac1 = 0.f, ac2 = 0.f, ac3 = 0.f;                          \
    _Pragma("unroll") for (int r = 0; r < 16; r += 4) {                        \
      const float p0 = __builtin_amdgcn_exp2f(S0_[r + 0] - m_run);             \
      const float p1 = __builtin_amdgcn_exp2f(S0_[r + 1] - m_run);             \
      const float p2 = __builtin_amdgcn_exp2f(S0_[r + 2] - m_run);             \
      const float p3 = __builtin_amdgcn_exp2f(S0_[r + 3] - m_run);             \
      S0_[r + 0] = p0; S0_[r + 1] = p1; S0_[r + 2] = p2; S0_[r + 3] = p3;      \
      ac0 += p0; ac1 += p1; ac2 += p2; ac3 += p3;                              \
    }                                                                          \
    _Pragma("unroll") for (int r = 0; r < 16; r += 4) {                        \
      const float p0 = __builtin_amdgcn_exp2f(S1_[r + 0] - m_run);             \
      const float p1 = __builtin_amdgcn_exp2f(S1_[r + 1] - m_run);             \
      const float p2 = __builtin_amdgcn_exp2f(S1_[r + 2] - m_run);             \
      const float p3 = __builtin_amdgcn_exp2f(S1_[r + 3] - m_run);             \
      S1_[r + 0] = p0; S1_[r + 1] = p1; S1_[r + 2] = p2; S1_[r + 3] = p3;      \
      ac0 += p0; ac1 += p1; ac2 += p2; ac3 += p3;                              \
    }                                                                          \
    float rs = (ac0 + ac1) + (ac2 + ac3);                                      \
    rs += __shfl_xor(rs, 32);                                                  \
    l_run += rs;                                                               \
    short8 pf[4];                                                              \
    _Pragma("unroll") for (int jk = 0; jk < 4; ++jk) {                         \
      const f32x16& ss = (jk < 2) ? S0_ : S1_;                                 \
      const int kk2 = jk & 1;                                                  \
      unsigned W0 = cvtpk(ss[8 * kk2 + 0], ss[8 * kk2 + 1]);                   \
      unsigned W1 = cvtpk(ss[8 * kk2 + 2], ss[8 * kk2 + 3]);                   \
      unsigned W2 = cvtpk(ss[8 * kk2 + 4], ss[8 * kk2 + 5]);                   \
      unsigned W3 = cvtpk(ss[8 * kk2 + 6], ss[8 * kk2 + 7]);                   \
      asm("v_permlane32_swap_b32 %0, %1" : "+v"(W0), "+v"(W2));                \
      asm("v_permlane32_swap_b32 %0, %1" : "+v"(W1), "+v"(W3));                \
      union { unsigned u[4]; short8 s; } pu;                                   \
      pu.u[0] = W0; pu.u[1] = W1; pu.u[2] = W2; pu.u[3] = W3;                  \
      pf[jk] = pu.s;                                                           \
    }                                                                          \
    __builtin_amdgcn_s_setprio(1);                                             \
    _Pragma("unroll") for (int kg = 0; kg < 4; ++kg) o0 = MFMA32(VF_[kg], pf[kg], o0); \
    _Pragma("unroll") for (int kg = 0; kg < 4; ++kg) o1 = MFMA32(VF_[4 + kg], pf[kg], o1); \
    __builtin_amdgcn_s_setprio(0);                                             \
  }

#define MASK_LAST(S0_, S1_)                                                    \
  { const int j0m = (nt - 1) * 64;                                             \
    if (j0m + 64 > len) {                                                      \
      _Pragma("unroll") for (int r = 0; r < 16; ++r) {                         \
        const int jl = (r & 3) + 8 * (r >> 2) + 4 * hi;                        \
        if (j0m + jl >= len) S0_[r] = -3.0e38f;                                \
        if (j0m + 32 + jl >= len) S1_[r] = -3.0e38f;                           \
      } } }

#define ATTN_BODY(JT, SP0, SP1, VFP, SN0, SN1, VFN)                            \
  { const int jc = (JT);                                                       \
    if (jc + 1 < nt) STAGE((jc + 1) & 1, (jc + 1) * 64);                       \
    QK_PART(jc, SN0, SN1)                                                      \
    SM_PV(SP0, SP1, VFP)                                                       \
    V_READ(jc, VFN)                                                            \
    __syncthreads(); }

__global__ __launch_bounds__(256) void attn_kernel(const u16* __restrict__ Kb, const u16* __restrict__ Qb,
                                                   const u16* __restrict__ Vtb, u16* __restrict__ attb,
                                                   const int* __restrict__ lens) {
  const int bid = blockIdx.x;
  const int b = bid >> 7;
  const int ic = (bid >> 3) & 7;
  const int h = ((bid & 7) << 1) | ((bid >> 6) & 1);
  const int len = lens[b];
  const int i0 = ic * 128;
  if (i0 >= len) return;  // fully-masked rows zeroed by final GEMM
  const int t = threadIdx.x;
  const int w = t >> 6, l = t & 63;
  const int l31 = l & 31, hi = l >> 5;
  const int i0w = i0 + w * 32;

  __shared__ u16 Qs[2][4096];  // 8KB per buffer
  __shared__ u16 Vs[2][4096];

  short8 kf[4];
  {
    const u16* kp = Kb + ((size_t)(b * NN + i0w + l31)) * DD + h * HD + hi * 8;
#pragma unroll
    for (int ks = 0; ks < 4; ++ks) kf[ks] = *(const short8*)(kp + ks * 16);
  }

  const size_t qsrc = ((size_t)(b * NN) + l31) * DD + h * HD + w * 16 + hi * 8;
  const size_t vsrc = ((size_t)((b * HH + h) * HD + l31)) * NN + w * 16 + hi * 8;

  auto STAGE = [&](int buf, int j0) {
    u16* qd = &Qs[buf][0] + t * 8;
    u16* vd = &Vs[buf][0] + t * 8;
    gld16(Qb + qsrc + (size_t)j0 * DD, qd);
    gld16(Qb + qsrc + (size_t)(j0 + 32) * DD, qd + 2048);
    gld16(Vtb + vsrc + j0, vd);
    gld16(Vtb + vsrc + 32 * NN + j0, vd + 2048);
  };

  f32x16 o0 = zero16(), o1 = zero16();
  float m_run = -3.0e38f, l_run = 0.f;
  const int nt = (len + 63) >> 6;  // >= 8 since len >= 512

  f32x16 sA0, sA1, sB0, sB1;
  short8 vfA[8], vfB[8];

  STAGE(0, 0);
  __syncthreads();
  if (nt > 1) STAGE(1, 64);
  QK_PART(0, sA0, sA1)
  V_READ(0, vfA)
  __syncthreads();

  int jt = 1;
  for (; jt + 1 < nt; jt += 2) {
    ATTN_BODY(jt, sA0, sA1, vfA, sB0, sB1, vfB)
    ATTN_BODY(jt + 1, sB0, sB1, vfB, sA0, sA1, vfA)
  }
  if (jt < nt) {
    ATTN_BODY(jt, sA0, sA1, vfA, sB0, sB1, vfB)
    MASK_LAST(sB0, sB1)
    SM_PV(sB0, sB1, vfB)
  } else {
    MASK_LAST(sA0, sA1)
    SM_PV(sA0, sA1, vfA)
  }

  const float inv = 1.f / l_run;
  u16* op = attb + (size_t)(b * NN + i0w + l31) * DD + h * HD + hi * 4;
#pragma unroll
  for (int xs = 0; xs < 2; ++xs) {
    const f32x16& oo = xs ? o1 : o0;
#pragma unroll
    for (int q = 0; q < 4; ++q) {
      short4v st;
#pragma unroll
      for (int e = 0; e < 4; ++e) st[e] = (short)f2bf(oo[q * 4 + e] * inv);
      *(short4v*)(op + xs * 32 + q * 8) = st;
    }
  }
}

// ---------------------------------------------------------------------------
extern "C" void kernel_launch(void* const* d_in, const int* in_sizes, int n_in,
                              void* d_out, int out_size, void* d_ws, size_t ws_size,
                              hipStream_t stream) {
  const float* x = (const float*)d_in[0];
  const unsigned char* mask = (const unsigned char*)d_in[1];
  const float* Wk = (const float*)d_in[2];
  const float* Wq = (const float*)d_in[3];
  const float* Wv = (const float*)d_in[4];
  const float* Wo = (const float*)d_in[5];
  const float* bo = (const float*)d_in[6];
  float* out = (float*)d_out;

  char* ws = (char*)d_ws;
  size_t o = 0;
  int* lens = (int*)(ws + o); o += 256;
  u16* xb  = (u16*)(ws + o); o += (size_t)MM * DD * 2;
  u16* wkb = (u16*)(ws + o); o += (size_t)DD * DD * 2;
  u16* wqb = (u16*)(ws + o); o += (size_t)DD * DD * 2;
  u16* wvb = (u16*)(ws + o); o += (size_t)DD * DD * 2;
  u16* wob = (u16*)(ws + o); o += (size_t)DD * DD * 2;
  u16* kb  = (u16*)(ws + o); o += (size_t)MM * DD * 2;
  u16* qb  = (u16*)(ws + o); o += (size_t)MM * DD * 2;
  u16* vtb = (u16*)(ws + o); o += (size_t)MM * DD * 2;
  u16* attb = xb;  // alias: x only needed until projections finish

  prep_kernel<<<dim3(6145), dim3(256), 0, stream>>>(x, Wk, Wq, Wv, Wo, xb, wkb, wqb, wvb,
                                                    wob, mask, lens);

  gemm_qkv<<<dim3(MM / 128, 24), dim3(256), 0, stream>>>(xb, wkb, wqb, wvb, kb, qb, vtb, lens);

  attn_kernel<<<dim3(1024), dim3(256), 0, stream>>>(kb, qb, vtb, attb, lens);

  gemm_out<<<dim3(MM / 128, DD / 128), dim3(256), 0, stream>>>(attb, wob, out, bo, lens);
}